// Round 1
// baseline (1375.534 us; speedup 1.0000x reference)
//
#include <hip/hip_runtime.h>

#define BATCHN 2
#define SEQL   2048
#define DM     1024
#define DI     2048
#define DSN    16
#define MTOT   (BATCHN * SEQL)   // 4096
#define PADL   (SEQL + 3)        // 2051

typedef __attribute__((ext_vector_type(8))) __bf16 bf16x8;
typedef __attribute__((ext_vector_type(4))) float f32x4;

__device__ __forceinline__ unsigned short f2b(float f) {
    union { float f; unsigned u; } v; v.f = f;
    unsigned r = v.u + 0x7FFF + ((v.u >> 16) & 1);
    return (unsigned short)(r >> 16);
}
__device__ __forceinline__ float b2f(unsigned short b) {
    union { float f; unsigned u; } v; v.u = ((unsigned)b) << 16;
    return v.f;
}

__device__ __forceinline__ void gl_lds16(const void* g, void* l) {
    __builtin_amdgcn_global_load_lds(
        (const __attribute__((address_space(1))) unsigned int*)g,
        (__attribute__((address_space(3))) unsigned int*)l, 16, 0, 0);
}

// ---------------- convert kernels ----------------
__global__ void cvt_f32_bf16(const float* __restrict__ src, unsigned short* __restrict__ dst, int n4) {
    int i = blockIdx.x * blockDim.x + threadIdx.x;
    if (i < n4) {
        float4 v = ((const float4*)src)[i];
        ushort4 o;
        o.x = f2b(v.x); o.y = f2b(v.y); o.z = f2b(v.z); o.w = f2b(v.w);
        ((ushort4*)dst)[i] = o;
    }
}

// conv_w (O,I,4) fp32 -> 4 planes wk[k][o][i] bf16
__global__ void cvt_convw(const float* __restrict__ cw, unsigned short* __restrict__ wk) {
    int i = blockIdx.x * blockDim.x + threadIdx.x;   // i = o*DI + ii
    if (i < DI * DI) {
        float4 v = ((const float4*)cw)[i];
        wk[0 * (size_t)DI * DI + i] = f2b(v.x);
        wk[1 * (size_t)DI * DI + i] = f2b(v.y);
        wk[2 * (size_t)DI * DI + i] = f2b(v.z);
        wk[3 * (size_t)DI * DI + i] = f2b(v.w);
    }
}

__global__ void zero_pad(unsigned short* __restrict__ xcpad) {
    int i = blockIdx.x * blockDim.x + threadIdx.x;
    if (i < BATCHN * 3 * DI) {
        int b = i / (3 * DI);
        int r = i % (3 * DI);
        xcpad[(size_t)b * PADL * DI + r] = 0;
    }
}

// ---------------- MFMA GEMM, B^T layout ----------------
// MODE 0: in_proj  A=x_bf [4096][1024], B=ipw [4096][1024], split-store xcpad / z_bf
// MODE 1: conv     A=xcpad (4 shifted segs), B=wk (4 planes [2048][2048]), +conv_b -> u_bf
// MODE 2: dt       A=u_bf [4096][2048], B=dtw [2048][2048], sigmoid-clip -> dt_f (fp32)
// MODE 3: out      A=y_bf [4096][2048], B=ow  [1024][2048], -> d_out fp32
template<int MODE>
__global__ void __launch_bounds__(256)
gemm_bt(const unsigned short* __restrict__ Abase,
        const unsigned short* __restrict__ Bbase,
        const float* __restrict__ bias,
        unsigned short* __restrict__ out_bf_a,
        unsigned short* __restrict__ out_bf_b,
        float* __restrict__ out_f,
        int K)
{
    __shared__ __align__(16) unsigned short As[128 * 64];
    __shared__ __align__(16) unsigned short Bs[128 * 64];

    const int t = threadIdx.x;
    const int lane = t & 63;
    const int wave = t >> 6;
    const int wm = wave & 1, wn = wave >> 1;
    const int m0 = blockIdx.y * 128, n0 = blockIdx.x * 128;
    const int srow = t >> 3;           // 0..31
    const int scol = (t & 7) * 8;      // bf16-element col offset (16B)

    f32x4 acc[4][4];
#pragma unroll
    for (int i = 0; i < 4; ++i)
#pragma unroll
        for (int j = 0; j < 4; ++j)
            acc[i][j] = f32x4{0.f, 0.f, 0.f, 0.f};

    const int nseg = (MODE == 1) ? 4 : 1;
    for (int seg = 0; seg < nseg; ++seg) {
        const unsigned short* arow[4];
        const unsigned short* brow[4];
#pragma unroll
        for (int i = 0; i < 4; ++i) {
            int rg = m0 + srow + i * 32;
            if (MODE == 1) {
                int bb = rg >> 11, ll = rg & 2047;
                arow[i] = Abase + ((size_t)bb * PADL + ll + seg) * DI;
            } else {
                arow[i] = Abase + (size_t)rg * K;
            }
            int ng = n0 + srow + i * 32;
            if (MODE == 1)
                brow[i] = Bbase + (size_t)seg * DI * DI + (size_t)ng * DI;
            else
                brow[i] = Bbase + (size_t)ng * K;
        }
        const int Kseg = (MODE == 1) ? DI : K;
        for (int k0 = 0; k0 < Kseg; k0 += 64) {
#pragma unroll
            for (int i = 0; i < 4; ++i)
                gl_lds16(arow[i] + k0 + scol, &As[(size_t)(srow + i * 32) * 64 + scol]);
#pragma unroll
            for (int i = 0; i < 4; ++i)
                gl_lds16(brow[i] + k0 + scol, &Bs[(size_t)(srow + i * 32) * 64 + scol]);
            __syncthreads();
            const int qa = (lane >> 4) * 8;
            const int am = lane & 15;
#pragma unroll
            for (int kk = 0; kk < 64; kk += 32) {
                bf16x8 af[4], bfv[4];
#pragma unroll
                for (int i = 0; i < 4; ++i)
                    af[i] = *(const bf16x8*)&As[(wm * 64 + i * 16 + am) * 64 + kk + qa];
#pragma unroll
                for (int j = 0; j < 4; ++j)
                    bfv[j] = *(const bf16x8*)&Bs[(wn * 64 + j * 16 + am) * 64 + kk + qa];
#pragma unroll
                for (int i = 0; i < 4; ++i)
#pragma unroll
                    for (int j = 0; j < 4; ++j)
                        acc[i][j] = __builtin_amdgcn_mfma_f32_16x16x32_bf16(
                            af[i], bfv[j], acc[i][j], 0, 0, 0);
            }
            __syncthreads();
        }
    }

    // epilogue: row = m0 + wm*64 + i*16 + (lane>>4)*4 + r ; col = n0 + wn*64 + j*16 + (lane&15)
    const int erow0 = m0 + wm * 64;
    const int ecol0 = n0 + wn * 64 + (lane & 15);
    const int rq = (lane >> 4) * 4;
#pragma unroll
    for (int i = 0; i < 4; ++i) {
#pragma unroll
        for (int j = 0; j < 4; ++j) {
            int col = ecol0 + j * 16;
#pragma unroll
            for (int r = 0; r < 4; ++r) {
                int row = erow0 + i * 16 + rq + r;
                float v = acc[i][j][r];
                if (MODE == 0) {
                    int bb = row >> 11, ll = row & 2047;
                    if (col < DI)
                        out_bf_a[((size_t)bb * PADL + 3 + ll) * DI + col] = f2b(v);
                    else
                        out_bf_b[(size_t)row * DI + (col - DI)] = f2b(v);
                } else if (MODE == 1) {
                    v += bias[col];
                    out_bf_a[(size_t)row * DI + col] = f2b(v);
                } else if (MODE == 2) {
                    v += bias[col];
                    float s = 1.f / (1.f + __expf(-v));
                    s = fminf(fmaxf(s, 1e-4f), 1.f);
                    out_f[(size_t)row * DI + col] = s;
                } else {
                    out_f[(size_t)row * DM + col] = v;
                }
            }
        }
    }
}

// ---------------- B/C projection (N=32) ----------------
__global__ void __launch_bounds__(256)
bc_gemm(const unsigned short* __restrict__ u,
        const unsigned short* __restrict__ w,
        float* __restrict__ outf)
{
    int t = threadIdx.x;
    int n = t & 31;
    int r = blockIdx.x * 8 + (t >> 5);
    const unsigned short* up = u + (size_t)r * DI;
    const unsigned short* wp = w + (size_t)n * DI;
    float acc = 0.f;
    for (int k0 = 0; k0 < DI; k0 += 8) {
        bf16x8 uv = *(const bf16x8*)(up + k0);
        bf16x8 wv = *(const bf16x8*)(wp + k0);
#pragma unroll
        for (int j = 0; j < 8; ++j)
            acc += (float)uv[j] * (float)wv[j];
    }
    outf[(size_t)r * 32 + n] = acc;
}

// ---------------- selective scan ----------------
// lane per (b, d, n): 16 lanes per d, shfl-xor reduce over n.
__global__ void __launch_bounds__(256)
scan_kernel(const float* __restrict__ dtf,
            const unsigned short* __restrict__ u_bf,
            const float* __restrict__ bcf,
            const unsigned short* __restrict__ z_bf,
            const float* __restrict__ A_log,
            const float* __restrict__ Dvec,
            unsigned short* __restrict__ y_bf)
{
    int t = threadIdx.x;
    int g = blockIdx.x;                 // 0..255
    int b = g >> 7;
    int d = ((g & 127) << 4) + (t >> 4);
    int n = t & 15;
    float Adn = -__expf(A_log[d * DSN + n]);
    float Dd = Dvec[d];
    float s = 0.f;
    size_t rowbase = (size_t)b * SEQL;
    for (int l0 = 0; l0 < SEQL; l0 += 4) {
        float dt4[4], u4[4], B4[4], C4[4], z4[4];
#pragma unroll
        for (int j = 0; j < 4; ++j) {
            size_t rb = rowbase + l0 + j;
            dt4[j] = dtf[rb * DI + d];
            u4[j] = b2f(u_bf[rb * DI + d]);
            B4[j] = bcf[rb * 32 + n];
            C4[j] = bcf[rb * 32 + 16 + n];
            z4[j] = b2f(z_bf[rb * DI + d]);
        }
#pragma unroll
        for (int j = 0; j < 4; ++j) {
            float x = dt4[j] * Adn;
            x = fminf(fmaxf(x, -5.f), 5.f);
            float dA = __expf(x);
            s = dA * s + (dt4[j] * B4[j] * u4[j] + 1e-6f);
            float p = s * C4[j];
            p += __shfl_xor(p, 1);
            p += __shfl_xor(p, 2);
            p += __shfl_xor(p, 4);
            p += __shfl_xor(p, 8);
            if (n == 0) {
                float y = p + Dd * u4[j];
                float zz = z4[j];
                y *= zz / (1.f + __expf(-zz));
                y_bf[(rowbase + l0 + j) * DI + d] = f2b(y);
            }
        }
    }
}

// ---------------- launch ----------------
extern "C" void kernel_launch(void* const* d_in, const int* in_sizes, int n_in,
                              void* d_out, int out_size, void* d_ws, size_t ws_size,
                              hipStream_t stream) {
    const float* x     = (const float*)d_in[0];
    const float* ipw   = (const float*)d_in[1];
    const float* convw = (const float*)d_in[2];
    const float* convb = (const float*)d_in[3];
    const float* dtw   = (const float*)d_in[4];
    const float* dtb   = (const float*)d_in[5];
    const float* alog  = (const float*)d_in[6];
    const float* dvec  = (const float*)d_in[7];
    const float* bw    = (const float*)d_in[8];
    const float* cwm   = (const float*)d_in[9];
    const float* ow    = (const float*)d_in[10];
    float* out = (float*)d_out;

    char* ws = (char*)d_ws;
    size_t off = 0;
    auto carve = [&](size_t bytes) {
        char* p = ws + off;
        off += (bytes + 255) & ~(size_t)255;
        return p;
    };
    unsigned short* x_bf   = (unsigned short*)carve((size_t)MTOT * DM * 2);
    unsigned short* ipw_bf = (unsigned short*)carve((size_t)2 * DI * DM * 2);
    unsigned short* wk_bf  = (unsigned short*)carve((size_t)4 * DI * DI * 2);
    unsigned short* dtw_bf = (unsigned short*)carve((size_t)DI * DI * 2);
    unsigned short* ow_bf  = (unsigned short*)carve((size_t)DM * DI * 2);
    unsigned short* bc_bf  = (unsigned short*)carve((size_t)2 * DSN * DI * 2);
    unsigned short* xcpad  = (unsigned short*)carve((size_t)BATCHN * PADL * DI * 2);
    unsigned short* z_bf   = (unsigned short*)carve((size_t)MTOT * DI * 2);
    unsigned short* u_bf   = (unsigned short*)carve((size_t)MTOT * DI * 2);
    float*          dt_f   = (float*)carve((size_t)MTOT * DI * 4);
    float*          bc_f   = (float*)carve((size_t)MTOT * 2 * DSN * 4);
    unsigned short* y_bf   = (unsigned short*)carve((size_t)MTOT * DI * 2);

    // converts
    {
        int n4 = MTOT * DM / 4;
        cvt_f32_bf16<<<(n4 + 255) / 256, 256, 0, stream>>>(x, x_bf, n4);
    }
    {
        int n4 = 2 * DI * DM / 4;
        cvt_f32_bf16<<<(n4 + 255) / 256, 256, 0, stream>>>(ipw, ipw_bf, n4);
    }
    {
        int n4 = DI * DI / 4;
        cvt_f32_bf16<<<(n4 + 255) / 256, 256, 0, stream>>>(dtw, dtw_bf, n4);
    }
    {
        int n4 = DM * DI / 4;
        cvt_f32_bf16<<<(n4 + 255) / 256, 256, 0, stream>>>(ow, ow_bf, n4);
    }
    {
        int n4 = DSN * DI / 4;
        cvt_f32_bf16<<<(n4 + 255) / 256, 256, 0, stream>>>(bw, bc_bf, n4);
        cvt_f32_bf16<<<(n4 + 255) / 256, 256, 0, stream>>>(cwm, bc_bf + (size_t)DSN * DI, n4);
    }
    {
        int n = DI * DI;
        cvt_convw<<<(n + 255) / 256, 256, 0, stream>>>(convw, wk_bf);
    }
    zero_pad<<<(BATCHN * 3 * DI + 255) / 256, 256, 0, stream>>>(xcpad);

    // in_proj: [4096,1024] x [4096,1024]^T
    gemm_bt<0><<<dim3(32, 32), 256, 0, stream>>>(x_bf, ipw_bf, nullptr, xcpad, z_bf, nullptr, DM);
    // conv: 4-seg K=2048 each
    gemm_bt<1><<<dim3(16, 32), 256, 0, stream>>>(xcpad, wk_bf, convb, u_bf, nullptr, nullptr, DI);
    // B/C projection
    bc_gemm<<<MTOT / 8, 256, 0, stream>>>(u_bf, bc_bf, bc_f);
    // dt projection + sigmoid/clip
    gemm_bt<2><<<dim3(16, 32), 256, 0, stream>>>(u_bf, dtw_bf, dtb, nullptr, nullptr, dt_f, DI);
    // scan (fused D*u + silu(z))
    scan_kernel<<<256, 256, 0, stream>>>(dt_f, u_bf, bc_f, z_bf, alog, dvec, y_bf);
    // out projection
    gemm_bt<3><<<dim3(8, 32), 256, 0, stream>>>(y_bf, ow_bf, nullptr, nullptr, nullptr, out, DI);
}

// Round 2
// 674.135 us; speedup vs baseline: 2.0404x; 2.0404x over previous
//
#include <hip/hip_runtime.h>

#define BATCHN 2
#define SEQL   2048
#define DM     1024
#define DI     2048
#define DSN    16
#define MTOT   (BATCHN * SEQL)   // 4096
#define PADL   (SEQL + 3)        // 2051
#define NC     64                // scan chunks
#define CL     (SEQL / NC)       // 32

typedef __attribute__((ext_vector_type(8))) __bf16 bf16x8;
typedef __attribute__((ext_vector_type(4))) float f32x4;

__device__ __forceinline__ unsigned short f2b(float f) {
    union { float f; unsigned u; } v; v.f = f;
    unsigned r = v.u + 0x7FFF + ((v.u >> 16) & 1);
    return (unsigned short)(r >> 16);
}
__device__ __forceinline__ float b2f(unsigned short b) {
    union { float f; unsigned u; } v; v.u = ((unsigned)b) << 16;
    return v.f;
}

__device__ __forceinline__ void gl_lds16(const void* g, void* l) {
    __builtin_amdgcn_global_load_lds(
        (const __attribute__((address_space(1))) unsigned int*)g,
        (__attribute__((address_space(3))) unsigned int*)l, 16, 0, 0);
}

// ---------------- convert kernels ----------------
__global__ void cvt_f32_bf16(const float* __restrict__ src, unsigned short* __restrict__ dst, int n4) {
    int i = blockIdx.x * blockDim.x + threadIdx.x;
    if (i < n4) {
        float4 v = ((const float4*)src)[i];
        ushort4 o;
        o.x = f2b(v.x); o.y = f2b(v.y); o.z = f2b(v.z); o.w = f2b(v.w);
        ((ushort4*)dst)[i] = o;
    }
}

// conv_w (O,I,4) fp32 -> 4 planes wk[k][o][i] bf16
__global__ void cvt_convw(const float* __restrict__ cw, unsigned short* __restrict__ wk) {
    int i = blockIdx.x * blockDim.x + threadIdx.x;   // i = o*DI + ii
    if (i < DI * DI) {
        float4 v = ((const float4*)cw)[i];
        wk[0 * (size_t)DI * DI + i] = f2b(v.x);
        wk[1 * (size_t)DI * DI + i] = f2b(v.y);
        wk[2 * (size_t)DI * DI + i] = f2b(v.z);
        wk[3 * (size_t)DI * DI + i] = f2b(v.w);
    }
}

__global__ void zero_pad(unsigned short* __restrict__ xcpad) {
    int i = blockIdx.x * blockDim.x + threadIdx.x;
    if (i < BATCHN * 3 * DI) {
        int b = i / (3 * DI);
        int r = i % (3 * DI);
        xcpad[(size_t)b * PADL * DI + r] = 0;
    }
}

// ---------------- MFMA GEMM, B^T layout ----------------
// MODE 0: in_proj  A=x_bf [4096][1024], B=ipw [4096][1024], split-store xcpad / z_bf
// MODE 1: conv     A=xcpad (4 shifted segs), B=wk (4 planes [2048][2048]), +conv_b -> u_bf
// MODE 2: dt       A=u_bf [4096][2048], B=dtw [2048][2048], sigmoid-clip -> dt_f (fp32)
// MODE 3: out      A=y_bf [4096][2048], B=ow  [1024][2048], -> d_out fp32
template<int MODE>
__global__ void __launch_bounds__(256)
gemm_bt(const unsigned short* __restrict__ Abase,
        const unsigned short* __restrict__ Bbase,
        const float* __restrict__ bias,
        unsigned short* __restrict__ out_bf_a,
        unsigned short* __restrict__ out_bf_b,
        float* __restrict__ out_f,
        int K)
{
    __shared__ __align__(16) unsigned short As[128 * 64];
    __shared__ __align__(16) unsigned short Bs[128 * 64];

    const int t = threadIdx.x;
    const int lane = t & 63;
    const int wave = t >> 6;
    const int wm = wave & 1, wn = wave >> 1;
    const int m0 = blockIdx.y * 128, n0 = blockIdx.x * 128;
    const int srow = t >> 3;           // 0..31
    const int scol = (t & 7) * 8;      // bf16-element col offset (16B)

    f32x4 acc[4][4];
#pragma unroll
    for (int i = 0; i < 4; ++i)
#pragma unroll
        for (int j = 0; j < 4; ++j)
            acc[i][j] = f32x4{0.f, 0.f, 0.f, 0.f};

    const int nseg = (MODE == 1) ? 4 : 1;
    for (int seg = 0; seg < nseg; ++seg) {
        const unsigned short* arow[4];
        const unsigned short* brow[4];
#pragma unroll
        for (int i = 0; i < 4; ++i) {
            int rg = m0 + srow + i * 32;
            if (MODE == 1) {
                int bb = rg >> 11, ll = rg & 2047;
                arow[i] = Abase + ((size_t)bb * PADL + ll + seg) * DI;
            } else {
                arow[i] = Abase + (size_t)rg * K;
            }
            int ng = n0 + srow + i * 32;
            if (MODE == 1)
                brow[i] = Bbase + (size_t)seg * DI * DI + (size_t)ng * DI;
            else
                brow[i] = Bbase + (size_t)ng * K;
        }
        const int Kseg = (MODE == 1) ? DI : K;
        for (int k0 = 0; k0 < Kseg; k0 += 64) {
#pragma unroll
            for (int i = 0; i < 4; ++i)
                gl_lds16(arow[i] + k0 + scol, &As[(size_t)(srow + i * 32) * 64 + scol]);
#pragma unroll
            for (int i = 0; i < 4; ++i)
                gl_lds16(brow[i] + k0 + scol, &Bs[(size_t)(srow + i * 32) * 64 + scol]);
            __syncthreads();
            const int qa = (lane >> 4) * 8;
            const int am = lane & 15;
#pragma unroll
            for (int kk = 0; kk < 64; kk += 32) {
                bf16x8 af[4], bfv[4];
#pragma unroll
                for (int i = 0; i < 4; ++i)
                    af[i] = *(const bf16x8*)&As[(wm * 64 + i * 16 + am) * 64 + kk + qa];
#pragma unroll
                for (int j = 0; j < 4; ++j)
                    bfv[j] = *(const bf16x8*)&Bs[(wn * 64 + j * 16 + am) * 64 + kk + qa];
#pragma unroll
                for (int i = 0; i < 4; ++i)
#pragma unroll
                    for (int j = 0; j < 4; ++j)
                        acc[i][j] = __builtin_amdgcn_mfma_f32_16x16x32_bf16(
                            af[i], bfv[j], acc[i][j], 0, 0, 0);
            }
            __syncthreads();
        }
    }

    // epilogue: row = m0 + wm*64 + i*16 + (lane>>4)*4 + r ; col = n0 + wn*64 + j*16 + (lane&15)
    const int erow0 = m0 + wm * 64;
    const int ecol0 = n0 + wn * 64 + (lane & 15);
    const int rq = (lane >> 4) * 4;
#pragma unroll
    for (int i = 0; i < 4; ++i) {
#pragma unroll
        for (int j = 0; j < 4; ++j) {
            int col = ecol0 + j * 16;
#pragma unroll
            for (int r = 0; r < 4; ++r) {
                int row = erow0 + i * 16 + rq + r;
                float v = acc[i][j][r];
                if (MODE == 0) {
                    int bb = row >> 11, ll = row & 2047;
                    if (col < DI)
                        out_bf_a[((size_t)bb * PADL + 3 + ll) * DI + col] = f2b(v);
                    else
                        out_bf_b[(size_t)row * DI + (col - DI)] = f2b(v);
                } else if (MODE == 1) {
                    v += bias[col];
                    out_bf_a[(size_t)row * DI + col] = f2b(v);
                } else if (MODE == 2) {
                    v += bias[col];
                    float s = 1.f / (1.f + __expf(-v));
                    s = fminf(fmaxf(s, 1e-4f), 1.f);
                    out_f[(size_t)row * DI + col] = s;
                } else {
                    out_f[(size_t)row * DM + col] = v;
                }
            }
        }
    }
}

// ---------------- B/C projection (N=32) ----------------
__global__ void __launch_bounds__(256)
bc_gemm(const unsigned short* __restrict__ u,
        const unsigned short* __restrict__ w,
        float* __restrict__ outf)
{
    int t = threadIdx.x;
    int n = t & 31;
    int r = blockIdx.x * 8 + (t >> 5);
    const unsigned short* up = u + (size_t)r * DI;
    const unsigned short* wp = w + (size_t)n * DI;
    float acc = 0.f;
    for (int k0 = 0; k0 < DI; k0 += 8) {
        bf16x8 uv = *(const bf16x8*)(up + k0);
        bf16x8 wv = *(const bf16x8*)(wp + k0);
#pragma unroll
        for (int j = 0; j < 8; ++j)
            acc += (float)uv[j] * (float)wv[j];
    }
    outf[(size_t)r * 32 + n] = acc;
}

// ---------------- chunked selective scan ----------------
// Phase 1: per (b,d,chunk) lane, all 16 n in registers.
// P[n] = prod dA over chunk; S[n] = chunk-local scan from 0.
// Buffers laid out [c][b][d][n] (idx = ((c*B + b)*DI + d)*16 + n).
__global__ void __launch_bounds__(256)
scan_p1(const float* __restrict__ dtf,
        const unsigned short* __restrict__ u_bf,
        const float* __restrict__ bcf,
        const float* __restrict__ A_log,
        float* __restrict__ Pbuf,
        float* __restrict__ Sbuf)
{
    const int t = threadIdx.x;
    const int blk = blockIdx.x;          // 1024 = c(64) x dh(8) x b(2)
    const int c  = blk & (NC - 1);
    const int dh = (blk >> 6) & 7;
    const int b  = blk >> 9;
    const int d  = dh * 256 + t;

    float Adn[16];
    {
        const float4* ar = (const float4*)(A_log + (size_t)d * DSN);
#pragma unroll
        for (int q = 0; q < 4; ++q) {
            float4 v = ar[q];
            Adn[q * 4 + 0] = -__expf(v.x);
            Adn[q * 4 + 1] = -__expf(v.y);
            Adn[q * 4 + 2] = -__expf(v.z);
            Adn[q * 4 + 3] = -__expf(v.w);
        }
    }
    float s[16], P[16];
#pragma unroll
    for (int n = 0; n < 16; ++n) { s[n] = 0.f; P[n] = 1.f; }

    const size_t rowbase = (size_t)b * SEQL + (size_t)c * CL;
    for (int l0 = 0; l0 < CL; l0 += 4) {
        float dt4[4], u4[4];
#pragma unroll
        for (int j = 0; j < 4; ++j) {
            size_t rb = rowbase + l0 + j;
            dt4[j] = dtf[rb * DI + d];
            u4[j] = b2f(u_bf[rb * DI + d]);
        }
#pragma unroll
        for (int j = 0; j < 4; ++j) {
            size_t rb = rowbase + l0 + j;
            const float4* Br = (const float4*)(bcf + rb * 32);
            float Bn[16];
#pragma unroll
            for (int q = 0; q < 4; ++q) {
                float4 v = Br[q];
                Bn[q * 4 + 0] = v.x; Bn[q * 4 + 1] = v.y;
                Bn[q * 4 + 2] = v.z; Bn[q * 4 + 3] = v.w;
            }
            float dt = dt4[j];
            float dBu = dt * u4[j];
#pragma unroll
            for (int n = 0; n < 16; ++n) {
                float x = dt * Adn[n];
                x = fminf(fmaxf(x, -5.f), 5.f);
                float dA = __expf(x);
                P[n] *= dA;
                s[n] = dA * s[n] + (dBu * Bn[n] + 1e-6f);
            }
        }
    }
    size_t ob = (((size_t)c * BATCHN + b) * DI + d) * DSN;
#pragma unroll
    for (int q = 0; q < 4; ++q) {
        ((float4*)(Pbuf + ob))[q] = make_float4(P[q*4], P[q*4+1], P[q*4+2], P[q*4+3]);
        ((float4*)(Sbuf + ob))[q] = make_float4(s[q*4], s[q*4+1], s[q*4+2], s[q*4+3]);
    }
}

// Phase 2: serial combine across chunks per (b,d,n). I[c] = incoming state.
__global__ void __launch_bounds__(256)
scan_p2(const float* __restrict__ Pbuf,
        const float* __restrict__ Sbuf,
        float* __restrict__ Ibuf)
{
    const int i = blockIdx.x * 256 + threadIdx.x;  // (b*DI+d)*16+n, 65536
    const int stride = BATCHN * DI * DSN;          // 65536
    float s = 0.f;
    for (int c0 = 0; c0 < NC; c0 += 8) {
        float Pv[8], Sv[8];
#pragma unroll
        for (int j = 0; j < 8; ++j) {
            size_t idx = (size_t)(c0 + j) * stride + i;
            Pv[j] = Pbuf[idx];
            Sv[j] = Sbuf[idx];
        }
#pragma unroll
        for (int j = 0; j < 8; ++j) {
            size_t idx = (size_t)(c0 + j) * stride + i;
            Ibuf[idx] = s;
            s = Pv[j] * s + Sv[j];
        }
    }
}

// Phase 3: re-run chunk from correct initial state, emit y (in-register n-sum).
__global__ void __launch_bounds__(256)
scan_p3(const float* __restrict__ dtf,
        const unsigned short* __restrict__ u_bf,
        const float* __restrict__ bcf,
        const unsigned short* __restrict__ z_bf,
        const float* __restrict__ A_log,
        const float* __restrict__ Dvec,
        const float* __restrict__ Ibuf,
        unsigned short* __restrict__ y_bf)
{
    const int t = threadIdx.x;
    const int blk = blockIdx.x;
    const int c  = blk & (NC - 1);
    const int dh = (blk >> 6) & 7;
    const int b  = blk >> 9;
    const int d  = dh * 256 + t;

    float Adn[16];
    {
        const float4* ar = (const float4*)(A_log + (size_t)d * DSN);
#pragma unroll
        for (int q = 0; q < 4; ++q) {
            float4 v = ar[q];
            Adn[q * 4 + 0] = -__expf(v.x);
            Adn[q * 4 + 1] = -__expf(v.y);
            Adn[q * 4 + 2] = -__expf(v.z);
            Adn[q * 4 + 3] = -__expf(v.w);
        }
    }
    const float Dd = Dvec[d];
    float s[16];
    {
        size_t ib = (((size_t)c * BATCHN + b) * DI + d) * DSN;
#pragma unroll
        for (int q = 0; q < 4; ++q) {
            float4 v = ((const float4*)(Ibuf + ib))[q];
            s[q * 4 + 0] = v.x; s[q * 4 + 1] = v.y;
            s[q * 4 + 2] = v.z; s[q * 4 + 3] = v.w;
        }
    }

    const size_t rowbase = (size_t)b * SEQL + (size_t)c * CL;
    for (int l0 = 0; l0 < CL; l0 += 4) {
        float dt4[4], u4[4], z4[4];
#pragma unroll
        for (int j = 0; j < 4; ++j) {
            size_t rb = rowbase + l0 + j;
            dt4[j] = dtf[rb * DI + d];
            u4[j] = b2f(u_bf[rb * DI + d]);
            z4[j] = b2f(z_bf[rb * DI + d]);
        }
#pragma unroll
        for (int j = 0; j < 4; ++j) {
            size_t rb = rowbase + l0 + j;
            const float4* Br = (const float4*)(bcf + rb * 32);
            float Bn[16], Cn[16];
#pragma unroll
            for (int q = 0; q < 4; ++q) {
                float4 v = Br[q];
                Bn[q * 4 + 0] = v.x; Bn[q * 4 + 1] = v.y;
                Bn[q * 4 + 2] = v.z; Bn[q * 4 + 3] = v.w;
                float4 w = Br[q + 4];
                Cn[q * 4 + 0] = w.x; Cn[q * 4 + 1] = w.y;
                Cn[q * 4 + 2] = w.z; Cn[q * 4 + 3] = w.w;
            }
            float dt = dt4[j];
            float dBu = dt * u4[j];
            float y = 0.f;
#pragma unroll
            for (int n = 0; n < 16; ++n) {
                float x = dt * Adn[n];
                x = fminf(fmaxf(x, -5.f), 5.f);
                float dA = __expf(x);
                s[n] = dA * s[n] + (dBu * Bn[n] + 1e-6f);
                y += s[n] * Cn[n];
            }
            y += Dd * u4[j];
            float zz = z4[j];
            y *= zz / (1.f + __expf(-zz));
            y_bf[rb * DI + d] = f2b(y);
        }
    }
}

// ---------------- launch ----------------
extern "C" void kernel_launch(void* const* d_in, const int* in_sizes, int n_in,
                              void* d_out, int out_size, void* d_ws, size_t ws_size,
                              hipStream_t stream) {
    const float* x     = (const float*)d_in[0];
    const float* ipw   = (const float*)d_in[1];
    const float* convw = (const float*)d_in[2];
    const float* convb = (const float*)d_in[3];
    const float* dtw   = (const float*)d_in[4];
    const float* dtb   = (const float*)d_in[5];
    const float* alog  = (const float*)d_in[6];
    const float* dvec  = (const float*)d_in[7];
    const float* bw    = (const float*)d_in[8];
    const float* cwm   = (const float*)d_in[9];
    const float* ow    = (const float*)d_in[10];
    float* out = (float*)d_out;

    char* ws = (char*)d_ws;
    size_t off = 0;
    auto carve = [&](size_t bytes) {
        char* p = ws + off;
        off += (bytes + 255) & ~(size_t)255;
        return p;
    };
    unsigned short* x_bf   = (unsigned short*)carve((size_t)MTOT * DM * 2);
    unsigned short* ipw_bf = (unsigned short*)carve((size_t)2 * DI * DM * 2);
    unsigned short* wk_bf  = (unsigned short*)carve((size_t)4 * DI * DI * 2);
    unsigned short* dtw_bf = (unsigned short*)carve((size_t)DI * DI * 2);
    unsigned short* ow_bf  = (unsigned short*)carve((size_t)DM * DI * 2);
    unsigned short* bc_bf  = (unsigned short*)carve((size_t)2 * DSN * DI * 2);
    unsigned short* xcpad  = (unsigned short*)carve((size_t)BATCHN * PADL * DI * 2);
    unsigned short* z_bf   = (unsigned short*)carve((size_t)MTOT * DI * 2);
    unsigned short* u_bf   = (unsigned short*)carve((size_t)MTOT * DI * 2);
    float*          dt_f   = (float*)carve((size_t)MTOT * DI * 4);
    float*          bc_f   = (float*)carve((size_t)MTOT * 2 * DSN * 4);
    unsigned short* y_bf   = (unsigned short*)carve((size_t)MTOT * DI * 2);
    float*          Pbuf   = (float*)carve((size_t)NC * BATCHN * DI * DSN * 4);
    float*          Sbuf   = (float*)carve((size_t)NC * BATCHN * DI * DSN * 4);
    float*          Ibuf   = (float*)carve((size_t)NC * BATCHN * DI * DSN * 4);

    // converts
    {
        int n4 = MTOT * DM / 4;
        cvt_f32_bf16<<<(n4 + 255) / 256, 256, 0, stream>>>(x, x_bf, n4);
    }
    {
        int n4 = 2 * DI * DM / 4;
        cvt_f32_bf16<<<(n4 + 255) / 256, 256, 0, stream>>>(ipw, ipw_bf, n4);
    }
    {
        int n4 = DI * DI / 4;
        cvt_f32_bf16<<<(n4 + 255) / 256, 256, 0, stream>>>(dtw, dtw_bf, n4);
    }
    {
        int n4 = DM * DI / 4;
        cvt_f32_bf16<<<(n4 + 255) / 256, 256, 0, stream>>>(ow, ow_bf, n4);
    }
    {
        int n4 = DSN * DI / 4;
        cvt_f32_bf16<<<(n4 + 255) / 256, 256, 0, stream>>>(bw, bc_bf, n4);
        cvt_f32_bf16<<<(n4 + 255) / 256, 256, 0, stream>>>(cwm, bc_bf + (size_t)DSN * DI, n4);
    }
    {
        int n = DI * DI;
        cvt_convw<<<(n + 255) / 256, 256, 0, stream>>>(convw, wk_bf);
    }
    zero_pad<<<(BATCHN * 3 * DI + 255) / 256, 256, 0, stream>>>(xcpad);

    // in_proj: [4096,1024] x [4096,1024]^T
    gemm_bt<0><<<dim3(32, 32), 256, 0, stream>>>(x_bf, ipw_bf, nullptr, xcpad, z_bf, nullptr, DM);
    // conv: 4-seg K=2048 each
    gemm_bt<1><<<dim3(16, 32), 256, 0, stream>>>(xcpad, wk_bf, convb, u_bf, nullptr, nullptr, DI);
    // B/C projection
    bc_gemm<<<MTOT / 8, 256, 0, stream>>>(u_bf, bc_bf, bc_f);
    // dt projection + sigmoid/clip
    gemm_bt<2><<<dim3(16, 32), 256, 0, stream>>>(u_bf, dtw_bf, dtb, nullptr, nullptr, dt_f, DI);
    // chunked scan
    scan_p1<<<BATCHN * 8 * NC, 256, 0, stream>>>(dt_f, u_bf, bc_f, alog, Pbuf, Sbuf);
    scan_p2<<<BATCHN * DI * DSN / 256, 256, 0, stream>>>(Pbuf, Sbuf, Ibuf);
    scan_p3<<<BATCHN * 8 * NC, 256, 0, stream>>>(dt_f, u_bf, bc_f, z_bf, alog, dvec, Ibuf, y_bf);
    // out projection
    gemm_bt<3><<<dim3(8, 32), 256, 0, stream>>>(y_bf, ow_bf, nullptr, nullptr, nullptr, out, DI);
}

// Round 3
// 616.445 us; speedup vs baseline: 2.2314x; 1.0936x over previous
//
#include <hip/hip_runtime.h>

#define BATCHN 2
#define SEQL   2048
#define DM     1024
#define DI     2048
#define DSN    16
#define MTOT   (BATCHN * SEQL)   // 4096
#define PADL   (SEQL + 3)        // 2051
#define NC     64                // scan chunks
#define CL     (SEQL / NC)       // 32

typedef __attribute__((ext_vector_type(8))) __bf16 bf16x8;
typedef __attribute__((ext_vector_type(4))) float f32x4;

__device__ __forceinline__ unsigned short f2b(float f) {
    union { float f; unsigned u; } v; v.f = f;
    unsigned r = v.u + 0x7FFF + ((v.u >> 16) & 1);
    return (unsigned short)(r >> 16);
}
__device__ __forceinline__ float b2f(unsigned short b) {
    union { float f; unsigned u; } v; v.u = ((unsigned)b) << 16;
    return v.f;
}

__device__ __forceinline__ void gl_lds16(const void* g, void* l) {
    __builtin_amdgcn_global_load_lds(
        (const __attribute__((address_space(1))) unsigned int*)g,
        (__attribute__((address_space(3))) unsigned int*)l, 16, 0, 0);
}

// ---------------- convert kernels ----------------
__global__ void cvt_f32_bf16(const float* __restrict__ src, unsigned short* __restrict__ dst, int n4) {
    int i = blockIdx.x * blockDim.x + threadIdx.x;
    if (i < n4) {
        float4 v = ((const float4*)src)[i];
        ushort4 o;
        o.x = f2b(v.x); o.y = f2b(v.y); o.z = f2b(v.z); o.w = f2b(v.w);
        ((ushort4*)dst)[i] = o;
    }
}

// conv_w (O,I,4) fp32 -> 4 planes wk[k][o][i] bf16
__global__ void cvt_convw(const float* __restrict__ cw, unsigned short* __restrict__ wk) {
    int i = blockIdx.x * blockDim.x + threadIdx.x;   // i = o*DI + ii
    if (i < DI * DI) {
        float4 v = ((const float4*)cw)[i];
        wk[0 * (size_t)DI * DI + i] = f2b(v.x);
        wk[1 * (size_t)DI * DI + i] = f2b(v.y);
        wk[2 * (size_t)DI * DI + i] = f2b(v.z);
        wk[3 * (size_t)DI * DI + i] = f2b(v.w);
    }
}

__global__ void zero_pad(unsigned short* __restrict__ xcpad) {
    int i = blockIdx.x * blockDim.x + threadIdx.x;
    if (i < BATCHN * 3 * DI) {
        int b = i / (3 * DI);
        int r = i % (3 * DI);
        xcpad[(size_t)b * PADL * DI + r] = 0;
    }
}

// ---------------- MFMA GEMM, B^T layout, XOR-swizzled LDS ----------------
// LDS physical colblk = global colblk ^ (row & 7); staging permutes the
// GLOBAL source per lane (LDS dest stays lane-contiguous for global_load_lds).
// MODE 0: in_proj  A=x_bf [4096][1024], B=ipw [4096][1024], split-store xcpad / z_bf
// MODE 1: conv     A=xcpad (4 shifted segs), B=wk (4 planes [2048][2048]), +conv_b -> u_bf
// MODE 2: dt       A=u_bf [4096][2048], B=dtw [2048][2048], sigmoid-clip -> dt_f (fp32)
// MODE 3: out      A=y_bf [4096][2048], B=ow  [1024][2048], -> d_out fp32
template<int MODE>
__global__ void __launch_bounds__(256)
gemm_bt(const unsigned short* __restrict__ Abase,
        const unsigned short* __restrict__ Bbase,
        const float* __restrict__ bias,
        unsigned short* __restrict__ out_bf_a,
        unsigned short* __restrict__ out_bf_b,
        float* __restrict__ out_f,
        int K)
{
    __shared__ __align__(16) unsigned short As[128 * 64];
    __shared__ __align__(16) unsigned short Bs[128 * 64];

    const int t = threadIdx.x;
    const int lane = t & 63;
    const int wave = t >> 6;
    const int wm = wave & 1, wn = wave >> 1;
    const int m0 = blockIdx.y * 128, n0 = blockIdx.x * 128;
    const int srow = t >> 3;                          // 0..31
    const int scol = (t & 7) * 8;                     // LDS physical col (bf16)
    const int gcol = (((t & 7) ^ (srow & 7))) * 8;    // swizzled global col

    f32x4 acc[4][4];
#pragma unroll
    for (int i = 0; i < 4; ++i)
#pragma unroll
        for (int j = 0; j < 4; ++j)
            acc[i][j] = f32x4{0.f, 0.f, 0.f, 0.f};

    const int nseg = (MODE == 1) ? 4 : 1;
    for (int seg = 0; seg < nseg; ++seg) {
        const unsigned short* arow[4];
        const unsigned short* brow[4];
#pragma unroll
        for (int i = 0; i < 4; ++i) {
            int rg = m0 + srow + i * 32;
            if (MODE == 1) {
                int bb = rg >> 11, ll = rg & 2047;
                arow[i] = Abase + ((size_t)bb * PADL + ll + seg) * DI;
            } else {
                arow[i] = Abase + (size_t)rg * K;
            }
            int ng = n0 + srow + i * 32;
            if (MODE == 1)
                brow[i] = Bbase + (size_t)seg * DI * DI + (size_t)ng * DI;
            else
                brow[i] = Bbase + (size_t)ng * K;
        }
        const int Kseg = (MODE == 1) ? DI : K;
        for (int k0 = 0; k0 < Kseg; k0 += 64) {
#pragma unroll
            for (int i = 0; i < 4; ++i)
                gl_lds16(arow[i] + k0 + gcol, &As[(size_t)(srow + i * 32) * 64 + scol]);
#pragma unroll
            for (int i = 0; i < 4; ++i)
                gl_lds16(brow[i] + k0 + gcol, &Bs[(size_t)(srow + i * 32) * 64 + scol]);
            __syncthreads();
            const int qa = (lane >> 4) * 8;
            const int am = lane & 15;
            const int sw = (am & 7) << 3;   // XOR swizzle on element col
#pragma unroll
            for (int kk = 0; kk < 64; kk += 32) {
                bf16x8 af[4], bfv[4];
#pragma unroll
                for (int i = 0; i < 4; ++i)
                    af[i] = *(const bf16x8*)&As[(wm * 64 + i * 16 + am) * 64 + ((kk + qa) ^ sw)];
#pragma unroll
                for (int j = 0; j < 4; ++j)
                    bfv[j] = *(const bf16x8*)&Bs[(wn * 64 + j * 16 + am) * 64 + ((kk + qa) ^ sw)];
#pragma unroll
                for (int i = 0; i < 4; ++i)
#pragma unroll
                    for (int j = 0; j < 4; ++j)
                        acc[i][j] = __builtin_amdgcn_mfma_f32_16x16x32_bf16(
                            af[i], bfv[j], acc[i][j], 0, 0, 0);
            }
            __syncthreads();
        }
    }

    // epilogue: row = m0 + wm*64 + i*16 + (lane>>4)*4 + r ; col = n0 + wn*64 + j*16 + (lane&15)
    const int erow0 = m0 + wm * 64;
    const int ecol0 = n0 + wn * 64 + (lane & 15);
    const int rq = (lane >> 4) * 4;
#pragma unroll
    for (int i = 0; i < 4; ++i) {
#pragma unroll
        for (int j = 0; j < 4; ++j) {
            int col = ecol0 + j * 16;
#pragma unroll
            for (int r = 0; r < 4; ++r) {
                int row = erow0 + i * 16 + rq + r;
                float v = acc[i][j][r];
                if (MODE == 0) {
                    int bb = row >> 11, ll = row & 2047;
                    if (col < DI)
                        out_bf_a[((size_t)bb * PADL + 3 + ll) * DI + col] = f2b(v);
                    else
                        out_bf_b[(size_t)row * DI + (col - DI)] = f2b(v);
                } else if (MODE == 1) {
                    v += bias[col];
                    out_bf_a[(size_t)row * DI + col] = f2b(v);
                } else if (MODE == 2) {
                    v += bias[col];
                    float s = 1.f / (1.f + __expf(-v));
                    s = fminf(fmaxf(s, 1e-4f), 1.f);
                    out_f[(size_t)row * DI + col] = s;
                } else {
                    out_f[(size_t)row * DM + col] = v;
                }
            }
        }
    }
}

// ---------------- B/C projection (N=32) ----------------
__global__ void __launch_bounds__(256)
bc_gemm(const unsigned short* __restrict__ u,
        const unsigned short* __restrict__ w,
        float* __restrict__ outf)
{
    int t = threadIdx.x;
    int n = t & 31;
    int r = blockIdx.x * 8 + (t >> 5);
    const unsigned short* up = u + (size_t)r * DI;
    const unsigned short* wp = w + (size_t)n * DI;
    float acc = 0.f;
    for (int k0 = 0; k0 < DI; k0 += 8) {
        bf16x8 uv = *(const bf16x8*)(up + k0);
        bf16x8 wv = *(const bf16x8*)(wp + k0);
#pragma unroll
        for (int j = 0; j < 8; ++j)
            acc += (float)uv[j] * (float)wv[j];
    }
    outf[(size_t)r * 32 + n] = acc;
}

// ---------------- chunked selective scan ----------------
// Phase 1: per (b,d,chunk) lane, all 16 n in registers.
// P[n] = prod dA over chunk; S[n] = chunk-local scan from 0.
// Buffers laid out [c][b][d][n] (idx = ((c*B + b)*DI + d)*16 + n).
__global__ void __launch_bounds__(256)
scan_p1(const float* __restrict__ dtf,
        const unsigned short* __restrict__ u_bf,
        const float* __restrict__ bcf,
        const float* __restrict__ A_log,
        float* __restrict__ Pbuf,
        float* __restrict__ Sbuf)
{
    const int t = threadIdx.x;
    const int blk = blockIdx.x;          // 1024 = c(64) x dh(8) x b(2)
    const int c  = blk & (NC - 1);
    const int dh = (blk >> 6) & 7;
    const int b  = blk >> 9;
    const int d  = dh * 256 + t;

    float Adn[16];
    {
        const float4* ar = (const float4*)(A_log + (size_t)d * DSN);
#pragma unroll
        for (int q = 0; q < 4; ++q) {
            float4 v = ar[q];
            Adn[q * 4 + 0] = -__expf(v.x);
            Adn[q * 4 + 1] = -__expf(v.y);
            Adn[q * 4 + 2] = -__expf(v.z);
            Adn[q * 4 + 3] = -__expf(v.w);
        }
    }
    float s[16], P[16];
#pragma unroll
    for (int n = 0; n < 16; ++n) { s[n] = 0.f; P[n] = 1.f; }

    const size_t rowbase = (size_t)b * SEQL + (size_t)c * CL;
    for (int l0 = 0; l0 < CL; l0 += 4) {
        float dt4[4], u4[4];
#pragma unroll
        for (int j = 0; j < 4; ++j) {
            size_t rb = rowbase + l0 + j;
            dt4[j] = dtf[rb * DI + d];
            u4[j] = b2f(u_bf[rb * DI + d]);
        }
#pragma unroll
        for (int j = 0; j < 4; ++j) {
            size_t rb = rowbase + l0 + j;
            const float4* Br = (const float4*)(bcf + rb * 32);
            float Bn[16];
#pragma unroll
            for (int q = 0; q < 4; ++q) {
                float4 v = Br[q];
                Bn[q * 4 + 0] = v.x; Bn[q * 4 + 1] = v.y;
                Bn[q * 4 + 2] = v.z; Bn[q * 4 + 3] = v.w;
            }
            float dt = dt4[j];
            float dBu = dt * u4[j];
#pragma unroll
            for (int n = 0; n < 16; ++n) {
                float x = dt * Adn[n];
                x = fminf(fmaxf(x, -5.f), 5.f);
                float dA = __expf(x);
                P[n] *= dA;
                s[n] = dA * s[n] + (dBu * Bn[n] + 1e-6f);
            }
        }
    }
    size_t ob = (((size_t)c * BATCHN + b) * DI + d) * DSN;
#pragma unroll
    for (int q = 0; q < 4; ++q) {
        ((float4*)(Pbuf + ob))[q] = make_float4(P[q*4], P[q*4+1], P[q*4+2], P[q*4+3]);
        ((float4*)(Sbuf + ob))[q] = make_float4(s[q*4], s[q*4+1], s[q*4+2], s[q*4+3]);
    }
}

// Phase 2: serial combine across chunks per (b,d,n). I[c] = incoming state.
__global__ void __launch_bounds__(256)
scan_p2(const float* __restrict__ Pbuf,
        const float* __restrict__ Sbuf,
        float* __restrict__ Ibuf)
{
    const int i = blockIdx.x * 256 + threadIdx.x;  // (b*DI+d)*16+n, 65536
    const int stride = BATCHN * DI * DSN;          // 65536
    float s = 0.f;
    for (int c0 = 0; c0 < NC; c0 += 8) {
        float Pv[8], Sv[8];
#pragma unroll
        for (int j = 0; j < 8; ++j) {
            size_t idx = (size_t)(c0 + j) * stride + i;
            Pv[j] = Pbuf[idx];
            Sv[j] = Sbuf[idx];
        }
#pragma unroll
        for (int j = 0; j < 8; ++j) {
            size_t idx = (size_t)(c0 + j) * stride + i;
            Ibuf[idx] = s;
            s = Pv[j] * s + Sv[j];
        }
    }
}

// Phase 3: re-run chunk from correct initial state, emit y (in-register n-sum).
__global__ void __launch_bounds__(256)
scan_p3(const float* __restrict__ dtf,
        const unsigned short* __restrict__ u_bf,
        const float* __restrict__ bcf,
        const unsigned short* __restrict__ z_bf,
        const float* __restrict__ A_log,
        const float* __restrict__ Dvec,
        const float* __restrict__ Ibuf,
        unsigned short* __restrict__ y_bf)
{
    const int t = threadIdx.x;
    const int blk = blockIdx.x;
    const int c  = blk & (NC - 1);
    const int dh = (blk >> 6) & 7;
    const int b  = blk >> 9;
    const int d  = dh * 256 + t;

    float Adn[16];
    {
        const float4* ar = (const float4*)(A_log + (size_t)d * DSN);
#pragma unroll
        for (int q = 0; q < 4; ++q) {
            float4 v = ar[q];
            Adn[q * 4 + 0] = -__expf(v.x);
            Adn[q * 4 + 1] = -__expf(v.y);
            Adn[q * 4 + 2] = -__expf(v.z);
            Adn[q * 4 + 3] = -__expf(v.w);
        }
    }
    const float Dd = Dvec[d];
    float s[16];
    {
        size_t ib = (((size_t)c * BATCHN + b) * DI + d) * DSN;
#pragma unroll
        for (int q = 0; q < 4; ++q) {
            float4 v = ((const float4*)(Ibuf + ib))[q];
            s[q * 4 + 0] = v.x; s[q * 4 + 1] = v.y;
            s[q * 4 + 2] = v.z; s[q * 4 + 3] = v.w;
        }
    }

    const size_t rowbase = (size_t)b * SEQL + (size_t)c * CL;
    for (int l0 = 0; l0 < CL; l0 += 4) {
        float dt4[4], u4[4], z4[4];
#pragma unroll
        for (int j = 0; j < 4; ++j) {
            size_t rb = rowbase + l0 + j;
            dt4[j] = dtf[rb * DI + d];
            u4[j] = b2f(u_bf[rb * DI + d]);
            z4[j] = b2f(z_bf[rb * DI + d]);
        }
#pragma unroll
        for (int j = 0; j < 4; ++j) {
            size_t rb = rowbase + l0 + j;
            const float4* Br = (const float4*)(bcf + rb * 32);
            float Bn[16], Cn[16];
#pragma unroll
            for (int q = 0; q < 4; ++q) {
                float4 v = Br[q];
                Bn[q * 4 + 0] = v.x; Bn[q * 4 + 1] = v.y;
                Bn[q * 4 + 2] = v.z; Bn[q * 4 + 3] = v.w;
                float4 w = Br[q + 4];
                Cn[q * 4 + 0] = w.x; Cn[q * 4 + 1] = w.y;
                Cn[q * 4 + 2] = w.z; Cn[q * 4 + 3] = w.w;
            }
            float dt = dt4[j];
            float dBu = dt * u4[j];
            float y = 0.f;
#pragma unroll
            for (int n = 0; n < 16; ++n) {
                float x = dt * Adn[n];
                x = fminf(fmaxf(x, -5.f), 5.f);
                float dA = __expf(x);
                s[n] = dA * s[n] + (dBu * Bn[n] + 1e-6f);
                y += s[n] * Cn[n];
            }
            y += Dd * u4[j];
            float zz = z4[j];
            y *= zz / (1.f + __expf(-zz));
            y_bf[rb * DI + d] = f2b(y);
        }
    }
}

// ---------------- launch ----------------
extern "C" void kernel_launch(void* const* d_in, const int* in_sizes, int n_in,
                              void* d_out, int out_size, void* d_ws, size_t ws_size,
                              hipStream_t stream) {
    const float* x     = (const float*)d_in[0];
    const float* ipw   = (const float*)d_in[1];
    const float* convw = (const float*)d_in[2];
    const float* convb = (const float*)d_in[3];
    const float* dtw   = (const float*)d_in[4];
    const float* dtb   = (const float*)d_in[5];
    const float* alog  = (const float*)d_in[6];
    const float* dvec  = (const float*)d_in[7];
    const float* bw    = (const float*)d_in[8];
    const float* cwm   = (const float*)d_in[9];
    const float* ow    = (const float*)d_in[10];
    float* out = (float*)d_out;

    char* ws = (char*)d_ws;
    size_t off = 0;
    auto carve = [&](size_t bytes) {
        char* p = ws + off;
        off += (bytes + 255) & ~(size_t)255;
        return p;
    };
    unsigned short* x_bf   = (unsigned short*)carve((size_t)MTOT * DM * 2);
    unsigned short* ipw_bf = (unsigned short*)carve((size_t)2 * DI * DM * 2);
    unsigned short* wk_bf  = (unsigned short*)carve((size_t)4 * DI * DI * 2);
    unsigned short* dtw_bf = (unsigned short*)carve((size_t)DI * DI * 2);
    unsigned short* ow_bf  = (unsigned short*)carve((size_t)DM * DI * 2);
    unsigned short* bc_bf  = (unsigned short*)carve((size_t)2 * DSN * DI * 2);
    unsigned short* xcpad  = (unsigned short*)carve((size_t)BATCHN * PADL * DI * 2);
    unsigned short* z_bf   = (unsigned short*)carve((size_t)MTOT * DI * 2);
    unsigned short* u_bf   = (unsigned short*)carve((size_t)MTOT * DI * 2);
    float*          dt_f   = (float*)carve((size_t)MTOT * DI * 4);
    float*          bc_f   = (float*)carve((size_t)MTOT * 2 * DSN * 4);
    unsigned short* y_bf   = (unsigned short*)carve((size_t)MTOT * DI * 2);
    float*          Pbuf   = (float*)carve((size_t)NC * BATCHN * DI * DSN * 4);
    float*          Sbuf   = (float*)carve((size_t)NC * BATCHN * DI * DSN * 4);
    float*          Ibuf   = (float*)carve((size_t)NC * BATCHN * DI * DSN * 4);

    // converts
    {
        int n4 = MTOT * DM / 4;
        cvt_f32_bf16<<<(n4 + 255) / 256, 256, 0, stream>>>(x, x_bf, n4);
    }
    {
        int n4 = 2 * DI * DM / 4;
        cvt_f32_bf16<<<(n4 + 255) / 256, 256, 0, stream>>>(ipw, ipw_bf, n4);
    }
    {
        int n4 = DI * DI / 4;
        cvt_f32_bf16<<<(n4 + 255) / 256, 256, 0, stream>>>(dtw, dtw_bf, n4);
    }
    {
        int n4 = DM * DI / 4;
        cvt_f32_bf16<<<(n4 + 255) / 256, 256, 0, stream>>>(ow, ow_bf, n4);
    }
    {
        int n4 = DSN * DI / 4;
        cvt_f32_bf16<<<(n4 + 255) / 256, 256, 0, stream>>>(bw, bc_bf, n4);
        cvt_f32_bf16<<<(n4 + 255) / 256, 256, 0, stream>>>(cwm, bc_bf + (size_t)DSN * DI, n4);
    }
    {
        int n = DI * DI;
        cvt_convw<<<(n + 255) / 256, 256, 0, stream>>>(convw, wk_bf);
    }
    zero_pad<<<(BATCHN * 3 * DI + 255) / 256, 256, 0, stream>>>(xcpad);

    // in_proj: [4096,1024] x [4096,1024]^T
    gemm_bt<0><<<dim3(32, 32), 256, 0, stream>>>(x_bf, ipw_bf, nullptr, xcpad, z_bf, nullptr, DM);
    // conv: 4-seg K=2048 each
    gemm_bt<1><<<dim3(16, 32), 256, 0, stream>>>(xcpad, wk_bf, convb, u_bf, nullptr, nullptr, DI);
    // B/C projection
    bc_gemm<<<MTOT / 8, 256, 0, stream>>>(u_bf, bc_bf, bc_f);
    // dt projection + sigmoid/clip
    gemm_bt<2><<<dim3(16, 32), 256, 0, stream>>>(u_bf, dtw_bf, dtb, nullptr, nullptr, dt_f, DI);
    // chunked scan
    scan_p1<<<BATCHN * 8 * NC, 256, 0, stream>>>(dt_f, u_bf, bc_f, alog, Pbuf, Sbuf);
    scan_p2<<<BATCHN * DI * DSN / 256, 256, 0, stream>>>(Pbuf, Sbuf, Ibuf);
    scan_p3<<<BATCHN * 8 * NC, 256, 0, stream>>>(dt_f, u_bf, bc_f, z_bf, alog, dvec, Ibuf, y_bf);
    // out projection
    gemm_bt<3><<<dim3(8, 32), 256, 0, stream>>>(y_bf, ow_bf, nullptr, nullptr, nullptr, out, DI);
}

// Round 4
// 547.962 us; speedup vs baseline: 2.5103x; 1.1250x over previous
//
#include <hip/hip_runtime.h>

#define BATCHN 2
#define SEQL   2048
#define DM     1024
#define DI     2048
#define DSN    16
#define MTOT   (BATCHN * SEQL)   // 4096
#define PADL   (SEQL + 3)        // 2051
#define NC     64                // scan chunks
#define CL     (SEQL / NC)       // 32

typedef __attribute__((ext_vector_type(8))) __bf16 bf16x8;
typedef __attribute__((ext_vector_type(4))) float f32x4;

__device__ __forceinline__ unsigned short f2b(float f) {
    union { float f; unsigned u; } v; v.f = f;
    unsigned r = v.u + 0x7FFF + ((v.u >> 16) & 1);
    return (unsigned short)(r >> 16);
}
__device__ __forceinline__ float b2f(unsigned short b) {
    union { float f; unsigned u; } v; v.u = ((unsigned)b) << 16;
    return v.f;
}

__device__ __forceinline__ void gl_lds16(const void* g, void* l) {
    __builtin_amdgcn_global_load_lds(
        (const __attribute__((address_space(1))) unsigned int*)g,
        (__attribute__((address_space(3))) unsigned int*)l, 16, 0, 0);
}

// XCD-aware block swizzle: 8 XCDs arranged 2 (x) x 4 (y) over the tile grid;
// each XCD covers a contiguous rectangle. Requires gx%2==0, gy%4==0.
__device__ __forceinline__ void swz(int& bx, int& by) {
    int gx = gridDim.x, gy = gridDim.y;
    int lin = blockIdx.y * gx + blockIdx.x;
    int xcd = lin & 7, k = lin >> 3;
    int rw = gx >> 1, rh = gy >> 2;
    by = (xcd >> 1) * rh + k / rw;
    bx = (xcd & 1) * rw + k % rw;
}

// ---------------- convert kernels ----------------
__global__ void cvt_f32_bf16(const float* __restrict__ src, unsigned short* __restrict__ dst, int n4) {
    int i = blockIdx.x * blockDim.x + threadIdx.x;
    if (i < n4) {
        float4 v = ((const float4*)src)[i];
        ushort4 o;
        o.x = f2b(v.x); o.y = f2b(v.y); o.z = f2b(v.z); o.w = f2b(v.w);
        ((ushort4*)dst)[i] = o;
    }
}

// x [b][l][c] fp32 -> xpad [b][3+l][c] bf16 (3 lead rows per batch left for zeros)
__global__ void cvt_x_pad(const float* __restrict__ src, unsigned short* __restrict__ dst) {
    int i = blockIdx.x * blockDim.x + threadIdx.x;   // float4 index
    if (i < MTOT * DM / 4) {
        int b = i >> 19;                             // / (2048*256)
        float4 v = ((const float4*)src)[i];
        ushort4 o;
        o.x = f2b(v.x); o.y = f2b(v.y); o.z = f2b(v.z); o.w = f2b(v.w);
        ((ushort4*)dst)[i + (b + 1) * (3 * DM / 4)] = o;
    }
}

// conv_w (O,I,4) fp32 -> 4 planes wk[k][o][i] bf16
__global__ void cvt_convw(const float* __restrict__ cw, unsigned short* __restrict__ wk) {
    int i = blockIdx.x * blockDim.x + threadIdx.x;   // i = o*DI + ii
    if (i < DI * DI) {
        float4 v = ((const float4*)cw)[i];
        wk[0 * (size_t)DI * DI + i] = f2b(v.x);
        wk[1 * (size_t)DI * DI + i] = f2b(v.y);
        wk[2 * (size_t)DI * DI + i] = f2b(v.z);
        wk[3 * (size_t)DI * DI + i] = f2b(v.w);
    }
}

// transpose-convert: ipw xc-half [i<2048][c<1024] fp32 -> Pt [c][i] bf16
__global__ void __launch_bounds__(256)
tp_cvt(const float* __restrict__ src, unsigned short* __restrict__ dst) {
    __shared__ float tile[32][33];
    int ct = blockIdx.x * 32, it = blockIdx.y * 32;
    int tx = threadIdx.x & 31, ty = threadIdx.x >> 5;   // 32 x 8
#pragma unroll
    for (int r = 0; r < 4; ++r)
        tile[ty + r * 8][tx] = src[(size_t)(it + ty + r * 8) * DM + ct + tx];
    __syncthreads();
#pragma unroll
    for (int r = 0; r < 4; ++r)
        dst[(size_t)(ct + ty + r * 8) * DI + it + tx] = f2b(tile[tx][ty + r * 8]);
}

__global__ void zero_pad(unsigned short* __restrict__ xpad) {
    int i = blockIdx.x * blockDim.x + threadIdx.x;
    if (i < BATCHN * 3 * DM) {
        int b = i / (3 * DM);
        int r = i % (3 * DM);
        xpad[(size_t)b * PADL * DM + r] = 0;
    }
}

// ---------------- MFMA GEMM, B^T layout, XOR-swizzled LDS, XCD swizzle ----
// MODE 0: z-proj   A=xpad(+3), B=ipz [2048][1024], K=1024 -> z_bf
// MODE 1: conv     A=xpad(+seg), B=mk planes [2048][1024], K=1024 x4segs, +conv_b -> u_bf
// MODE 2: dt       A=u_bf, B=dtw [2048][2048], K=2048, sigmoid-clip -> dt_f (fp32)
// MODE 3: out      A=y_bf, B=ow [1024][2048], K=2048 -> d_out fp32
// MODE 4: mk-fuse  A=wk plane z [2048][2048], B=Pt [1024][2048], K=2048 -> mk plane z bf16
template<int MODE>
__global__ void __launch_bounds__(256)
gemm_bt(const unsigned short* __restrict__ Abase,
        const unsigned short* __restrict__ Bbase,
        const float* __restrict__ bias,
        unsigned short* __restrict__ out_bf,
        float* __restrict__ out_f,
        int K)
{
    __shared__ __align__(16) unsigned short As[128 * 64];
    __shared__ __align__(16) unsigned short Bs[128 * 64];

    const int t = threadIdx.x;
    const int lane = t & 63;
    const int wave = t >> 6;
    const int wm = wave & 1, wn = wave >> 1;
    int bx, by;
    swz(bx, by);
    const int m0 = by * 128, n0 = bx * 128;
    const int srow = t >> 3;                          // 0..31
    const int scol = (t & 7) * 8;                     // LDS physical col (bf16)
    const int gcol = (((t & 7) ^ (srow & 7))) * 8;    // swizzled global col

    f32x4 acc[4][4];
#pragma unroll
    for (int i = 0; i < 4; ++i)
#pragma unroll
        for (int j = 0; j < 4; ++j)
            acc[i][j] = f32x4{0.f, 0.f, 0.f, 0.f};

    const int nseg = (MODE == 1) ? 4 : 1;
    for (int seg = 0; seg < nseg; ++seg) {
        const unsigned short* arow[4];
        const unsigned short* brow[4];
#pragma unroll
        for (int i = 0; i < 4; ++i) {
            int rg = m0 + srow + i * 32;
            if (MODE == 0) {
                arow[i] = Abase + ((size_t)(rg >> 11) * PADL + 3 + (rg & 2047)) * DM;
            } else if (MODE == 1) {
                arow[i] = Abase + ((size_t)(rg >> 11) * PADL + (rg & 2047) + seg) * DM;
            } else if (MODE == 4) {
                arow[i] = Abase + (size_t)blockIdx.z * DI * DI + (size_t)rg * K;
            } else {
                arow[i] = Abase + (size_t)rg * K;
            }
            int ng = n0 + srow + i * 32;
            if (MODE == 1)
                brow[i] = Bbase + (size_t)seg * DI * DM + (size_t)ng * DM;
            else
                brow[i] = Bbase + (size_t)ng * K;
        }
        const int Kseg = (MODE == 1) ? DM : K;
        for (int k0 = 0; k0 < Kseg; k0 += 64) {
#pragma unroll
            for (int i = 0; i < 4; ++i)
                gl_lds16(arow[i] + k0 + gcol, &As[(size_t)(srow + i * 32) * 64 + scol]);
#pragma unroll
            for (int i = 0; i < 4; ++i)
                gl_lds16(brow[i] + k0 + gcol, &Bs[(size_t)(srow + i * 32) * 64 + scol]);
            __syncthreads();
            const int qa = (lane >> 4) * 8;
            const int am = lane & 15;
            const int sw = (am & 7) << 3;   // XOR swizzle on element col
#pragma unroll
            for (int kk = 0; kk < 64; kk += 32) {
                bf16x8 af[4], bfv[4];
#pragma unroll
                for (int i = 0; i < 4; ++i)
                    af[i] = *(const bf16x8*)&As[(wm * 64 + i * 16 + am) * 64 + ((kk + qa) ^ sw)];
#pragma unroll
                for (int j = 0; j < 4; ++j)
                    bfv[j] = *(const bf16x8*)&Bs[(wn * 64 + j * 16 + am) * 64 + ((kk + qa) ^ sw)];
#pragma unroll
                for (int i = 0; i < 4; ++i)
#pragma unroll
                    for (int j = 0; j < 4; ++j)
                        acc[i][j] = __builtin_amdgcn_mfma_f32_16x16x32_bf16(
                            af[i], bfv[j], acc[i][j], 0, 0, 0);
            }
            __syncthreads();
        }
    }

    // epilogue: row = m0 + wm*64 + i*16 + (lane>>4)*4 + r ; col = n0 + wn*64 + j*16 + (lane&15)
    const int erow0 = m0 + wm * 64;
    const int ecol0 = n0 + wn * 64 + (lane & 15);
    const int rq = (lane >> 4) * 4;
#pragma unroll
    for (int i = 0; i < 4; ++i) {
#pragma unroll
        for (int j = 0; j < 4; ++j) {
            int col = ecol0 + j * 16;
#pragma unroll
            for (int r = 0; r < 4; ++r) {
                int row = erow0 + i * 16 + rq + r;
                float v = acc[i][j][r];
                if (MODE == 0) {
                    out_bf[(size_t)row * DI + col] = f2b(v);
                } else if (MODE == 1) {
                    v += bias[col];
                    out_bf[(size_t)row * DI + col] = f2b(v);
                } else if (MODE == 2) {
                    v += bias[col];
                    float s = 1.f / (1.f + __expf(-v));
                    s = fminf(fmaxf(s, 1e-4f), 1.f);
                    out_f[(size_t)row * DI + col] = s;
                } else if (MODE == 3) {
                    out_f[(size_t)row * DM + col] = v;
                } else { // MODE 4
                    out_bf[(size_t)blockIdx.z * DI * DM + (size_t)row * DM + col] = f2b(v);
                }
            }
        }
    }
}

// ---------------- B/C projection (N=32) ----------------
__global__ void __launch_bounds__(256)
bc_gemm(const unsigned short* __restrict__ u,
        const unsigned short* __restrict__ w,
        float* __restrict__ outf)
{
    int t = threadIdx.x;
    int n = t & 31;
    int r = blockIdx.x * 8 + (t >> 5);
    const unsigned short* up = u + (size_t)r * DI;
    const unsigned short* wp = w + (size_t)n * DI;
    float acc = 0.f;
    for (int k0 = 0; k0 < DI; k0 += 8) {
        bf16x8 uv = *(const bf16x8*)(up + k0);
        bf16x8 wv = *(const bf16x8*)(wp + k0);
#pragma unroll
        for (int j = 0; j < 8; ++j)
            acc += (float)uv[j] * (float)wv[j];
    }
    outf[(size_t)r * 32 + n] = acc;
}

// ---------------- chunked selective scan ----------------
// Phase 1: per (b,d,chunk) lane, all 16 n in registers.
__global__ void __launch_bounds__(256)
scan_p1(const float* __restrict__ dtf,
        const unsigned short* __restrict__ u_bf,
        const float* __restrict__ bcf,
        const float* __restrict__ A_log,
        float* __restrict__ Pbuf,
        float* __restrict__ Sbuf)
{
    const int t = threadIdx.x;
    const int blk = blockIdx.x;          // 1024 = c(64) x dh(8) x b(2)
    const int c  = blk & (NC - 1);
    const int dh = (blk >> 6) & 7;
    const int b  = blk >> 9;
    const int d  = dh * 256 + t;

    float Adn[16];
    {
        const float4* ar = (const float4*)(A_log + (size_t)d * DSN);
#pragma unroll
        for (int q = 0; q < 4; ++q) {
            float4 v = ar[q];
            Adn[q * 4 + 0] = -__expf(v.x);
            Adn[q * 4 + 1] = -__expf(v.y);
            Adn[q * 4 + 2] = -__expf(v.z);
            Adn[q * 4 + 3] = -__expf(v.w);
        }
    }
    float s[16], P[16];
#pragma unroll
    for (int n = 0; n < 16; ++n) { s[n] = 0.f; P[n] = 1.f; }

    const size_t rowbase = (size_t)b * SEQL + (size_t)c * CL;
    for (int l0 = 0; l0 < CL; l0 += 4) {
        float dt4[4], u4[4];
#pragma unroll
        for (int j = 0; j < 4; ++j) {
            size_t rb = rowbase + l0 + j;
            dt4[j] = dtf[rb * DI + d];
            u4[j] = b2f(u_bf[rb * DI + d]);
        }
#pragma unroll
        for (int j = 0; j < 4; ++j) {
            size_t rb = rowbase + l0 + j;
            const float4* Br = (const float4*)(bcf + rb * 32);
            float Bn[16];
#pragma unroll
            for (int q = 0; q < 4; ++q) {
                float4 v = Br[q];
                Bn[q * 4 + 0] = v.x; Bn[q * 4 + 1] = v.y;
                Bn[q * 4 + 2] = v.z; Bn[q * 4 + 3] = v.w;
            }
            float dt = dt4[j];
            float dBu = dt * u4[j];
#pragma unroll
            for (int n = 0; n < 16; ++n) {
                float x = dt * Adn[n];
                x = fminf(fmaxf(x, -5.f), 5.f);
                float dA = __expf(x);
                P[n] *= dA;
                s[n] = dA * s[n] + (dBu * Bn[n] + 1e-6f);
            }
        }
    }
    size_t ob = (((size_t)c * BATCHN + b) * DI + d) * DSN;
#pragma unroll
    for (int q = 0; q < 4; ++q) {
        ((float4*)(Pbuf + ob))[q] = make_float4(P[q*4], P[q*4+1], P[q*4+2], P[q*4+3]);
        ((float4*)(Sbuf + ob))[q] = make_float4(s[q*4], s[q*4+1], s[q*4+2], s[q*4+3]);
    }
}

// Phase 2: serial combine across chunks per (b,d,n). I[c] = incoming state.
__global__ void __launch_bounds__(256)
scan_p2(const float* __restrict__ Pbuf,
        const float* __restrict__ Sbuf,
        float* __restrict__ Ibuf)
{
    const int i = blockIdx.x * 256 + threadIdx.x;  // (b*DI+d)*16+n, 65536
    const int stride = BATCHN * DI * DSN;          // 65536
    float s = 0.f;
    for (int c0 = 0; c0 < NC; c0 += 8) {
        float Pv[8], Sv[8];
#pragma unroll
        for (int j = 0; j < 8; ++j) {
            size_t idx = (size_t)(c0 + j) * stride + i;
            Pv[j] = Pbuf[idx];
            Sv[j] = Sbuf[idx];
        }
#pragma unroll
        for (int j = 0; j < 8; ++j) {
            size_t idx = (size_t)(c0 + j) * stride + i;
            Ibuf[idx] = s;
            s = Pv[j] * s + Sv[j];
        }
    }
}

// Phase 3: re-run chunk from correct initial state, emit y (in-register n-sum).
__global__ void __launch_bounds__(256)
scan_p3(const float* __restrict__ dtf,
        const unsigned short* __restrict__ u_bf,
        const float* __restrict__ bcf,
        const unsigned short* __restrict__ z_bf,
        const float* __restrict__ A_log,
        const float* __restrict__ Dvec,
        const float* __restrict__ Ibuf,
        unsigned short* __restrict__ y_bf)
{
    const int t = threadIdx.x;
    const int blk = blockIdx.x;
    const int c  = blk & (NC - 1);
    const int dh = (blk >> 6) & 7;
    const int b  = blk >> 9;
    const int d  = dh * 256 + t;

    float Adn[16];
    {
        const float4* ar = (const float4*)(A_log + (size_t)d * DSN);
#pragma unroll
        for (int q = 0; q < 4; ++q) {
            float4 v = ar[q];
            Adn[q * 4 + 0] = -__expf(v.x);
            Adn[q * 4 + 1] = -__expf(v.y);
            Adn[q * 4 + 2] = -__expf(v.z);
            Adn[q * 4 + 3] = -__expf(v.w);
        }
    }
    const float Dd = Dvec[d];
    float s[16];
    {
        size_t ib = (((size_t)c * BATCHN + b) * DI + d) * DSN;
#pragma unroll
        for (int q = 0; q < 4; ++q) {
            float4 v = ((const float4*)(Ibuf + ib))[q];
            s[q * 4 + 0] = v.x; s[q * 4 + 1] = v.y;
            s[q * 4 + 2] = v.z; s[q * 4 + 3] = v.w;
        }
    }

    const size_t rowbase = (size_t)b * SEQL + (size_t)c * CL;
    for (int l0 = 0; l0 < CL; l0 += 4) {
        float dt4[4], u4[4], z4[4];
#pragma unroll
        for (int j = 0; j < 4; ++j) {
            size_t rb = rowbase + l0 + j;
            dt4[j] = dtf[rb * DI + d];
            u4[j] = b2f(u_bf[rb * DI + d]);
            z4[j] = b2f(z_bf[rb * DI + d]);
        }
#pragma unroll
        for (int j = 0; j < 4; ++j) {
            size_t rb = rowbase + l0 + j;
            const float4* Br = (const float4*)(bcf + rb * 32);
            float Bn[16], Cn[16];
#pragma unroll
            for (int q = 0; q < 4; ++q) {
                float4 v = Br[q];
                Bn[q * 4 + 0] = v.x; Bn[q * 4 + 1] = v.y;
                Bn[q * 4 + 2] = v.z; Bn[q * 4 + 3] = v.w;
                float4 w = Br[q + 4];
                Cn[q * 4 + 0] = w.x; Cn[q * 4 + 1] = w.y;
                Cn[q * 4 + 2] = w.z; Cn[q * 4 + 3] = w.w;
            }
            float dt = dt4[j];
            float dBu = dt * u4[j];
            float y = 0.f;
#pragma unroll
            for (int n = 0; n < 16; ++n) {
                float x = dt * Adn[n];
                x = fminf(fmaxf(x, -5.f), 5.f);
                float dA = __expf(x);
                s[n] = dA * s[n] + (dBu * Bn[n] + 1e-6f);
                y += s[n] * Cn[n];
            }
            y += Dd * u4[j];
            float zz = z4[j];
            y *= zz / (1.f + __expf(-zz));
            y_bf[rb * DI + d] = f2b(y);
        }
    }
}

// ---------------- launch ----------------
extern "C" void kernel_launch(void* const* d_in, const int* in_sizes, int n_in,
                              void* d_out, int out_size, void* d_ws, size_t ws_size,
                              hipStream_t stream) {
    const float* x     = (const float*)d_in[0];
    const float* ipw   = (const float*)d_in[1];
    const float* convw = (const float*)d_in[2];
    const float* convb = (const float*)d_in[3];
    const float* dtw   = (const float*)d_in[4];
    const float* dtb   = (const float*)d_in[5];
    const float* alog  = (const float*)d_in[6];
    const float* dvec  = (const float*)d_in[7];
    const float* bw    = (const float*)d_in[8];
    const float* cwm   = (const float*)d_in[9];
    const float* ow    = (const float*)d_in[10];
    float* out = (float*)d_out;

    char* ws = (char*)d_ws;
    size_t off = 0;
    auto carve = [&](size_t bytes) {
        char* p = ws + off;
        off += (bytes + 255) & ~(size_t)255;
        return p;
    };
    unsigned short* xpad   = (unsigned short*)carve((size_t)BATCHN * PADL * DM * 2);
    unsigned short* ipz_bf = (unsigned short*)carve((size_t)DI * DM * 2);
    unsigned short* Pt_bf  = (unsigned short*)carve((size_t)DM * DI * 2);
    unsigned short* wk_bf  = (unsigned short*)carve((size_t)4 * DI * DI * 2);
    unsigned short* mk_bf  = (unsigned short*)carve((size_t)4 * DI * DM * 2);
    unsigned short* dtw_bf = (unsigned short*)carve((size_t)DI * DI * 2);
    unsigned short* ow_bf  = (unsigned short*)carve((size_t)DM * DI * 2);
    unsigned short* bc_bf  = (unsigned short*)carve((size_t)2 * DSN * DI * 2);
    unsigned short* z_bf   = (unsigned short*)carve((size_t)MTOT * DI * 2);
    unsigned short* u_bf   = (unsigned short*)carve((size_t)MTOT * DI * 2);
    float*          dt_f   = (float*)carve((size_t)MTOT * DI * 4);
    float*          bc_f   = (float*)carve((size_t)MTOT * 2 * DSN * 4);
    unsigned short* y_bf   = (unsigned short*)carve((size_t)MTOT * DI * 2);
    float*          Pbuf   = (float*)carve((size_t)NC * BATCHN * DI * DSN * 4);
    float*          Sbuf   = (float*)carve((size_t)NC * BATCHN * DI * DSN * 4);
    float*          Ibuf   = (float*)carve((size_t)NC * BATCHN * DI * DSN * 4);

    // converts
    cvt_x_pad<<<MTOT * DM / 4 / 256, 256, 0, stream>>>(x, xpad);
    zero_pad<<<(BATCHN * 3 * DM + 255) / 256, 256, 0, stream>>>(xpad);
    cvt_convw<<<DI * DI / 256, 256, 0, stream>>>(convw, wk_bf);
    tp_cvt<<<dim3(DM / 32, DI / 32), 256, 0, stream>>>(ipw, Pt_bf);
    cvt_f32_bf16<<<DI * DM / 4 / 256, 256, 0, stream>>>(ipw + (size_t)DI * DM, ipz_bf, DI * DM / 4);
    cvt_f32_bf16<<<DI * DI / 4 / 256, 256, 0, stream>>>(dtw, dtw_bf, DI * DI / 4);
    cvt_f32_bf16<<<DM * DI / 4 / 256, 256, 0, stream>>>(ow, ow_bf, DM * DI / 4);
    cvt_f32_bf16<<<(DSN * DI / 4 + 255) / 256, 256, 0, stream>>>(bw, bc_bf, DSN * DI / 4);
    cvt_f32_bf16<<<(DSN * DI / 4 + 255) / 256, 256, 0, stream>>>(cwm, bc_bf + (size_t)DSN * DI, DSN * DI / 4);

    // mk-fuse: Mk = W_k @ P_xc   [2048][1024] x4 planes
    gemm_bt<4><<<dim3(8, 16, 4), 256, 0, stream>>>(wk_bf, Pt_bf, nullptr, mk_bf, nullptr, DI);
    // z-proj: z = x @ ipz^T
    gemm_bt<0><<<dim3(16, 32), 256, 0, stream>>>(xpad, ipz_bf, nullptr, z_bf, nullptr, DM);
    // conv (fused): u = sum_k x[l-3+k] @ Mk^T + conv_b
    gemm_bt<1><<<dim3(16, 32), 256, 0, stream>>>(xpad, mk_bf, convb, u_bf, nullptr, DM);
    // B/C projection
    bc_gemm<<<MTOT / 8, 256, 0, stream>>>(u_bf, bc_bf, bc_f);
    // dt projection + sigmoid/clip
    gemm_bt<2><<<dim3(16, 32), 256, 0, stream>>>(u_bf, dtw_bf, dtb, nullptr, dt_f, DI);
    // chunked scan
    scan_p1<<<BATCHN * 8 * NC, 256, 0, stream>>>(dt_f, u_bf, bc_f, alog, Pbuf, Sbuf);
    scan_p2<<<BATCHN * DI * DSN / 256, 256, 0, stream>>>(Pbuf, Sbuf, Ibuf);
    scan_p3<<<BATCHN * 8 * NC, 256, 0, stream>>>(dt_f, u_bf, bc_f, z_bf, alog, dvec, Ibuf, y_bf);
    // out projection
    gemm_bt<3><<<dim3(8, 32), 256, 0, stream>>>(y_bf, ow_bf, nullptr, nullptr, out, DI);
}

// Round 5
// 487.120 us; speedup vs baseline: 2.8238x; 1.1249x over previous
//
#include <hip/hip_runtime.h>

#define BATCHN 2
#define SEQL   2048
#define DM     1024
#define DI     2048
#define DSN    16
#define MTOT   (BATCHN * SEQL)   // 4096
#define PADL   (SEQL + 3)        // 2051
#define NC     64                // scan chunks
#define CL     (SEQL / NC)       // 32
#define BCKS   8                 // bc split-K factor

typedef __attribute__((ext_vector_type(8))) __bf16 bf16x8;
typedef __attribute__((ext_vector_type(4))) float f32x4;

__device__ __forceinline__ unsigned short f2b(float f) {
    union { float f; unsigned u; } v; v.f = f;
    unsigned r = v.u + 0x7FFF + ((v.u >> 16) & 1);
    return (unsigned short)(r >> 16);
}
__device__ __forceinline__ float b2f(unsigned short b) {
    union { float f; unsigned u; } v; v.u = ((unsigned)b) << 16;
    return v.f;
}

__device__ __forceinline__ void gl_lds16(const void* g, void* l) {
    __builtin_amdgcn_global_load_lds(
        (const __attribute__((address_space(1))) unsigned int*)g,
        (__attribute__((address_space(3))) unsigned int*)l, 16, 0, 0);
}

// XCD-aware block swizzle: 8 XCDs arranged 2 (x) x 4 (y) over the tile grid;
// each XCD covers a contiguous rectangle. Requires gx%2==0, gy%4==0.
__device__ __forceinline__ void swz(int& bx, int& by) {
    int gx = gridDim.x, gy = gridDim.y;
    int lin = blockIdx.y * gx + blockIdx.x;
    int xcd = lin & 7, k = lin >> 3;
    int rw = gx >> 1, rh = gy >> 2;
    by = (xcd >> 1) * rh + k / rw;
    bx = (xcd & 1) * rw + k % rw;
}

// ---------------- convert kernels ----------------
__global__ void cvt_f32_bf16(const float* __restrict__ src, unsigned short* __restrict__ dst, int n4) {
    int i = blockIdx.x * blockDim.x + threadIdx.x;
    if (i < n4) {
        float4 v = ((const float4*)src)[i];
        ushort4 o;
        o.x = f2b(v.x); o.y = f2b(v.y); o.z = f2b(v.z); o.w = f2b(v.w);
        ((ushort4*)dst)[i] = o;
    }
}

// x [b][l][c] fp32 -> xpad [b][3+l][c] bf16 (3 lead rows per batch left for zeros)
__global__ void cvt_x_pad(const float* __restrict__ src, unsigned short* __restrict__ dst) {
    int i = blockIdx.x * blockDim.x + threadIdx.x;   // float4 index
    if (i < MTOT * DM / 4) {
        int b = i >> 19;                             // / (2048*256)
        float4 v = ((const float4*)src)[i];
        ushort4 o;
        o.x = f2b(v.x); o.y = f2b(v.y); o.z = f2b(v.z); o.w = f2b(v.w);
        ((ushort4*)dst)[i + (b + 1) * (3 * DM / 4)] = o;
    }
}

// conv_w (O,I,4) fp32 -> 4 planes wk[k][o][i] bf16
__global__ void cvt_convw(const float* __restrict__ cw, unsigned short* __restrict__ wk) {
    int i = blockIdx.x * blockDim.x + threadIdx.x;   // i = o*DI + ii
    if (i < DI * DI) {
        float4 v = ((const float4*)cw)[i];
        wk[0 * (size_t)DI * DI + i] = f2b(v.x);
        wk[1 * (size_t)DI * DI + i] = f2b(v.y);
        wk[2 * (size_t)DI * DI + i] = f2b(v.z);
        wk[3 * (size_t)DI * DI + i] = f2b(v.w);
    }
}

// transpose-convert: ipw xc-half [i<2048][c<1024] fp32 -> Pt [c][i] bf16
__global__ void __launch_bounds__(256)
tp_cvt(const float* __restrict__ src, unsigned short* __restrict__ dst) {
    __shared__ float tile[32][33];
    int ct = blockIdx.x * 32, it = blockIdx.y * 32;
    int tx = threadIdx.x & 31, ty = threadIdx.x >> 5;   // 32 x 8
#pragma unroll
    for (int r = 0; r < 4; ++r)
        tile[ty + r * 8][tx] = src[(size_t)(it + ty + r * 8) * DM + ct + tx];
    __syncthreads();
#pragma unroll
    for (int r = 0; r < 4; ++r)
        dst[(size_t)(ct + ty + r * 8) * DI + it + tx] = f2b(tile[tx][ty + r * 8]);
}

__global__ void zero_pad(unsigned short* __restrict__ xpad) {
    int i = blockIdx.x * blockDim.x + threadIdx.x;
    if (i < BATCHN * 3 * DM) {
        int b = i / (3 * DM);
        int r = i % (3 * DM);
        xpad[(size_t)b * PADL * DM + r] = 0;
    }
}

// ---------------- MFMA GEMM, B^T layout, XOR-swizzled LDS, XCD swizzle ----
// MODE 0: z-proj   A=xpad(+3), B=ipz [2048][1024], K=1024 -> z_bf
// MODE 1: conv     A=xpad(+seg), B=mk planes [2048][1024], K=1024 x4segs, +conv_b -> u_bf
// MODE 2: dt       A=u_bf, B=dtw [2048][2048], K=2048, sigmoid-clip -> dt_f (fp32)
// MODE 3: out      A=y_bf, B=ow [1024][2048], K=2048 -> d_out fp32
// MODE 4: mk-fuse  A=wk plane z [2048][2048], B=Pt [1024][2048], K=2048 -> mk plane z bf16
template<int MODE>
__global__ void __launch_bounds__(256)
gemm_bt(const unsigned short* __restrict__ Abase,
        const unsigned short* __restrict__ Bbase,
        const float* __restrict__ bias,
        unsigned short* __restrict__ out_bf,
        float* __restrict__ out_f,
        int K)
{
    __shared__ __align__(16) unsigned short As[128 * 64];
    __shared__ __align__(16) unsigned short Bs[128 * 64];

    const int t = threadIdx.x;
    const int lane = t & 63;
    const int wave = t >> 6;
    const int wm = wave & 1, wn = wave >> 1;
    int bx, by;
    swz(bx, by);
    const int m0 = by * 128, n0 = bx * 128;
    const int srow = t >> 3;                          // 0..31
    const int scol = (t & 7) * 8;                     // LDS physical col (bf16)
    const int gcol = (((t & 7) ^ (srow & 7))) * 8;    // swizzled global col

    f32x4 acc[4][4];
#pragma unroll
    for (int i = 0; i < 4; ++i)
#pragma unroll
        for (int j = 0; j < 4; ++j)
            acc[i][j] = f32x4{0.f, 0.f, 0.f, 0.f};

    const int nseg = (MODE == 1) ? 4 : 1;
    for (int seg = 0; seg < nseg; ++seg) {
        const unsigned short* arow[4];
        const unsigned short* brow[4];
#pragma unroll
        for (int i = 0; i < 4; ++i) {
            int rg = m0 + srow + i * 32;
            if (MODE == 0) {
                arow[i] = Abase + ((size_t)(rg >> 11) * PADL + 3 + (rg & 2047)) * DM;
            } else if (MODE == 1) {
                arow[i] = Abase + ((size_t)(rg >> 11) * PADL + (rg & 2047) + seg) * DM;
            } else if (MODE == 4) {
                arow[i] = Abase + (size_t)blockIdx.z * DI * DI + (size_t)rg * K;
            } else {
                arow[i] = Abase + (size_t)rg * K;
            }
            int ng = n0 + srow + i * 32;
            if (MODE == 1)
                brow[i] = Bbase + (size_t)seg * DI * DM + (size_t)ng * DM;
            else
                brow[i] = Bbase + (size_t)ng * K;
        }
        const int Kseg = (MODE == 1) ? DM : K;
        for (int k0 = 0; k0 < Kseg; k0 += 64) {
#pragma unroll
            for (int i = 0; i < 4; ++i)
                gl_lds16(arow[i] + k0 + gcol, &As[(size_t)(srow + i * 32) * 64 + scol]);
#pragma unroll
            for (int i = 0; i < 4; ++i)
                gl_lds16(brow[i] + k0 + gcol, &Bs[(size_t)(srow + i * 32) * 64 + scol]);
            __syncthreads();
            const int qa = (lane >> 4) * 8;
            const int am = lane & 15;
            const int sw = (am & 7) << 3;   // XOR swizzle on element col
#pragma unroll
            for (int kk = 0; kk < 64; kk += 32) {
                bf16x8 af[4], bfv[4];
#pragma unroll
                for (int i = 0; i < 4; ++i)
                    af[i] = *(const bf16x8*)&As[(wm * 64 + i * 16 + am) * 64 + ((kk + qa) ^ sw)];
#pragma unroll
                for (int j = 0; j < 4; ++j)
                    bfv[j] = *(const bf16x8*)&Bs[(wn * 64 + j * 16 + am) * 64 + ((kk + qa) ^ sw)];
#pragma unroll
                for (int i = 0; i < 4; ++i)
#pragma unroll
                    for (int j = 0; j < 4; ++j)
                        acc[i][j] = __builtin_amdgcn_mfma_f32_16x16x32_bf16(
                            af[i], bfv[j], acc[i][j], 0, 0, 0);
            }
            __syncthreads();
        }
    }

    // epilogue: row = m0 + wm*64 + i*16 + (lane>>4)*4 + r ; col = n0 + wn*64 + j*16 + (lane&15)
    const int erow0 = m0 + wm * 64;
    const int ecol0 = n0 + wn * 64 + (lane & 15);
    const int rq = (lane >> 4) * 4;
#pragma unroll
    for (int i = 0; i < 4; ++i) {
#pragma unroll
        for (int j = 0; j < 4; ++j) {
            int col = ecol0 + j * 16;
#pragma unroll
            for (int r = 0; r < 4; ++r) {
                int row = erow0 + i * 16 + rq + r;
                float v = acc[i][j][r];
                if (MODE == 0) {
                    out_bf[(size_t)row * DI + col] = f2b(v);
                } else if (MODE == 1) {
                    v += bias[col];
                    out_bf[(size_t)row * DI + col] = f2b(v);
                } else if (MODE == 2) {
                    v += bias[col];
                    float s = 1.f / (1.f + __expf(-v));
                    s = fminf(fmaxf(s, 1e-4f), 1.f);
                    out_f[(size_t)row * DI + col] = s;
                } else if (MODE == 3) {
                    out_f[(size_t)row * DM + col] = v;
                } else { // MODE 4
                    out_bf[(size_t)blockIdx.z * DI * DM + (size_t)row * DM + col] = f2b(v);
                }
            }
        }
    }
}

// ---------------- B/C projection: MFMA split-K ----------------
// u [4096][2048] x w [32][2048]^T -> pc [BCKS][4096][32] partials.
// Per block: 128 rows x 32 cols over a K=2048/BCKS slice. 4 waves x 32 rows.
__global__ void __launch_bounds__(256)
bc_mfma(const unsigned short* __restrict__ u,
        const unsigned short* __restrict__ w,
        float* __restrict__ pc)
{
    const int t = threadIdx.x;
    const int lane = t & 63;
    const int wave = t >> 6;
    const int ks = blockIdx.x;                    // 0..BCKS-1
    const int m0 = blockIdx.y * 128 + wave * 32;
    const int am = lane & 15, quad = lane >> 4;

    f32x4 acc[2][2];
#pragma unroll
    for (int i = 0; i < 2; ++i)
#pragma unroll
        for (int j = 0; j < 2; ++j)
            acc[i][j] = f32x4{0.f, 0.f, 0.f, 0.f};

    const int kbase = ks * (DI / BCKS);
    const unsigned short* ur0 = u + (size_t)(m0 + am) * DI;
    const unsigned short* ur1 = u + (size_t)(m0 + 16 + am) * DI;
    const unsigned short* wr0 = w + (size_t)am * DI;
    const unsigned short* wr1 = w + (size_t)(16 + am) * DI;
#pragma unroll 2
    for (int kk = 0; kk < DI / BCKS; kk += 32) {
        int k = kbase + kk + quad * 8;
        bf16x8 a0 = *(const bf16x8*)(ur0 + k);
        bf16x8 a1 = *(const bf16x8*)(ur1 + k);
        bf16x8 b0 = *(const bf16x8*)(wr0 + k);
        bf16x8 b1 = *(const bf16x8*)(wr1 + k);
        acc[0][0] = __builtin_amdgcn_mfma_f32_16x16x32_bf16(a0, b0, acc[0][0], 0, 0, 0);
        acc[0][1] = __builtin_amdgcn_mfma_f32_16x16x32_bf16(a0, b1, acc[0][1], 0, 0, 0);
        acc[1][0] = __builtin_amdgcn_mfma_f32_16x16x32_bf16(a1, b0, acc[1][0], 0, 0, 0);
        acc[1][1] = __builtin_amdgcn_mfma_f32_16x16x32_bf16(a1, b1, acc[1][1], 0, 0, 0);
    }
    float* base = pc + (size_t)ks * MTOT * 32;
#pragma unroll
    for (int i = 0; i < 2; ++i)
#pragma unroll
        for (int j = 0; j < 2; ++j)
#pragma unroll
            for (int r = 0; r < 4; ++r) {
                int row = m0 + i * 16 + quad * 4 + r;
                int col = j * 16 + am;
                base[(size_t)row * 32 + col] = acc[i][j][r];
            }
}

__global__ void __launch_bounds__(256)
bc_reduce(const float* __restrict__ pc, float* __restrict__ outf)
{
    int i = blockIdx.x * 256 + threadIdx.x;       // float4 index, 32768 total
    const float4* p4 = (const float4*)pc;
    float4 s = p4[i];
#pragma unroll
    for (int ks = 1; ks < BCKS; ++ks) {
        float4 v = p4[(size_t)ks * (MTOT * 8) + i];
        s.x += v.x; s.y += v.y; s.z += v.z; s.w += v.w;
    }
    ((float4*)outf)[i] = s;
}

// ---------------- chunked selective scan ----------------
// Phase 1: per (b,d,chunk) lane, all 16 n in registers.
__global__ void __launch_bounds__(256)
scan_p1(const float* __restrict__ dtf,
        const unsigned short* __restrict__ u_bf,
        const float* __restrict__ bcf,
        const float* __restrict__ A_log,
        float* __restrict__ Pbuf,
        float* __restrict__ Sbuf)
{
    const int t = threadIdx.x;
    const int blk = blockIdx.x;          // 1024 = c(64) x dh(8) x b(2)
    const int c  = blk & (NC - 1);
    const int dh = (blk >> 6) & 7;
    const int b  = blk >> 9;
    const int d  = dh * 256 + t;

    float Adn[16];
    {
        const float4* ar = (const float4*)(A_log + (size_t)d * DSN);
#pragma unroll
        for (int q = 0; q < 4; ++q) {
            float4 v = ar[q];
            Adn[q * 4 + 0] = -__expf(v.x);
            Adn[q * 4 + 1] = -__expf(v.y);
            Adn[q * 4 + 2] = -__expf(v.z);
            Adn[q * 4 + 3] = -__expf(v.w);
        }
    }
    float s[16], P[16];
#pragma unroll
    for (int n = 0; n < 16; ++n) { s[n] = 0.f; P[n] = 1.f; }

    const size_t rowbase = (size_t)b * SEQL + (size_t)c * CL;
    for (int l0 = 0; l0 < CL; l0 += 4) {
        float dt4[4], u4[4];
#pragma unroll
        for (int j = 0; j < 4; ++j) {
            size_t rb = rowbase + l0 + j;
            dt4[j] = dtf[rb * DI + d];
            u4[j] = b2f(u_bf[rb * DI + d]);
        }
#pragma unroll
        for (int j = 0; j < 4; ++j) {
            size_t rb = rowbase + l0 + j;
            const float4* Br = (const float4*)(bcf + rb * 32);
            float Bn[16];
#pragma unroll
            for (int q = 0; q < 4; ++q) {
                float4 v = Br[q];
                Bn[q * 4 + 0] = v.x; Bn[q * 4 + 1] = v.y;
                Bn[q * 4 + 2] = v.z; Bn[q * 4 + 3] = v.w;
            }
            float dt = dt4[j];
            float dBu = dt * u4[j];
#pragma unroll
            for (int n = 0; n < 16; ++n) {
                float x = dt * Adn[n];
                x = fminf(fmaxf(x, -5.f), 5.f);
                float dA = __expf(x);
                P[n] *= dA;
                s[n] = dA * s[n] + (dBu * Bn[n] + 1e-6f);
            }
        }
    }
    size_t ob = (((size_t)c * BATCHN + b) * DI + d) * DSN;
#pragma unroll
    for (int q = 0; q < 4; ++q) {
        ((float4*)(Pbuf + ob))[q] = make_float4(P[q*4], P[q*4+1], P[q*4+2], P[q*4+3]);
        ((float4*)(Sbuf + ob))[q] = make_float4(s[q*4], s[q*4+1], s[q*4+2], s[q*4+3]);
    }
}

// Phase 2: serial combine across chunks per (b,d,n). I[c] = incoming state.
__global__ void __launch_bounds__(256)
scan_p2(const float* __restrict__ Pbuf,
        const float* __restrict__ Sbuf,
        float* __restrict__ Ibuf)
{
    const int i = blockIdx.x * 256 + threadIdx.x;  // (b*DI+d)*16+n, 65536
    const int stride = BATCHN * DI * DSN;          // 65536
    float s = 0.f;
    for (int c0 = 0; c0 < NC; c0 += 8) {
        float Pv[8], Sv[8];
#pragma unroll
        for (int j = 0; j < 8; ++j) {
            size_t idx = (size_t)(c0 + j) * stride + i;
            Pv[j] = Pbuf[idx];
            Sv[j] = Sbuf[idx];
        }
#pragma unroll
        for (int j = 0; j < 8; ++j) {
            size_t idx = (size_t)(c0 + j) * stride + i;
            Ibuf[idx] = s;
            s = Pv[j] * s + Sv[j];
        }
    }
}

// Phase 3: re-run chunk from correct initial state, emit y (in-register n-sum).
__global__ void __launch_bounds__(256)
scan_p3(const float* __restrict__ dtf,
        const unsigned short* __restrict__ u_bf,
        const float* __restrict__ bcf,
        const unsigned short* __restrict__ z_bf,
        const float* __restrict__ A_log,
        const float* __restrict__ Dvec,
        const float* __restrict__ Ibuf,
        unsigned short* __restrict__ y_bf)
{
    const int t = threadIdx.x;
    const int blk = blockIdx.x;
    const int c  = blk & (NC - 1);
    const int dh = (blk >> 6) & 7;
    const int b  = blk >> 9;
    const int d  = dh * 256 + t;

    float Adn[16];
    {
        const float4* ar = (const float4*)(A_log + (size_t)d * DSN);
#pragma unroll
        for (int q = 0; q < 4; ++q) {
            float4 v = ar[q];
            Adn[q * 4 + 0] = -__expf(v.x);
            Adn[q * 4 + 1] = -__expf(v.y);
            Adn[q * 4 + 2] = -__expf(v.z);
            Adn[q * 4 + 3] = -__expf(v.w);
        }
    }
    const float Dd = Dvec[d];
    float s[16];
    {
        size_t ib = (((size_t)c * BATCHN + b) * DI + d) * DSN;
#pragma unroll
        for (int q = 0; q < 4; ++q) {
            float4 v = ((const float4*)(Ibuf + ib))[q];
            s[q * 4 + 0] = v.x; s[q * 4 + 1] = v.y;
            s[q * 4 + 2] = v.z; s[q * 4 + 3] = v.w;
        }
    }

    const size_t rowbase = (size_t)b * SEQL + (size_t)c * CL;
    for (int l0 = 0; l0 < CL; l0 += 4) {
        float dt4[4], u4[4], z4[4];
#pragma unroll
        for (int j = 0; j < 4; ++j) {
            size_t rb = rowbase + l0 + j;
            dt4[j] = dtf[rb * DI + d];
            u4[j] = b2f(u_bf[rb * DI + d]);
            z4[j] = b2f(z_bf[rb * DI + d]);
        }
#pragma unroll
        for (int j = 0; j < 4; ++j) {
            size_t rb = rowbase + l0 + j;
            const float4* Br = (const float4*)(bcf + rb * 32);
            float Bn[16], Cn[16];
#pragma unroll
            for (int q = 0; q < 4; ++q) {
                float4 v = Br[q];
                Bn[q * 4 + 0] = v.x; Bn[q * 4 + 1] = v.y;
                Bn[q * 4 + 2] = v.z; Bn[q * 4 + 3] = v.w;
                float4 w = Br[q + 4];
                Cn[q * 4 + 0] = w.x; Cn[q * 4 + 1] = w.y;
                Cn[q * 4 + 2] = w.z; Cn[q * 4 + 3] = w.w;
            }
            float dt = dt4[j];
            float dBu = dt * u4[j];
            float y = 0.f;
#pragma unroll
            for (int n = 0; n < 16; ++n) {
                float x = dt * Adn[n];
                x = fminf(fmaxf(x, -5.f), 5.f);
                float dA = __expf(x);
                s[n] = dA * s[n] + (dBu * Bn[n] + 1e-6f);
                y += s[n] * Cn[n];
            }
            y += Dd * u4[j];
            float zz = z4[j];
            y *= zz / (1.f + __expf(-zz));
            y_bf[rb * DI + d] = f2b(y);
        }
    }
}

// ---------------- launch ----------------
extern "C" void kernel_launch(void* const* d_in, const int* in_sizes, int n_in,
                              void* d_out, int out_size, void* d_ws, size_t ws_size,
                              hipStream_t stream) {
    const float* x     = (const float*)d_in[0];
    const float* ipw   = (const float*)d_in[1];
    const float* convw = (const float*)d_in[2];
    const float* convb = (const float*)d_in[3];
    const float* dtw   = (const float*)d_in[4];
    const float* dtb   = (const float*)d_in[5];
    const float* alog  = (const float*)d_in[6];
    const float* dvec  = (const float*)d_in[7];
    const float* bw    = (const float*)d_in[8];
    const float* cwm   = (const float*)d_in[9];
    const float* ow    = (const float*)d_in[10];
    float* out = (float*)d_out;

    char* ws = (char*)d_ws;
    size_t off = 0;
    auto carve = [&](size_t bytes) {
        char* p = ws + off;
        off += (bytes + 255) & ~(size_t)255;
        return p;
    };
    unsigned short* xpad   = (unsigned short*)carve((size_t)BATCHN * PADL * DM * 2);
    unsigned short* ipz_bf = (unsigned short*)carve((size_t)DI * DM * 2);
    unsigned short* Pt_bf  = (unsigned short*)carve((size_t)DM * DI * 2);
    unsigned short* wk_bf  = (unsigned short*)carve((size_t)4 * DI * DI * 2);
    unsigned short* mk_bf  = (unsigned short*)carve((size_t)4 * DI * DM * 2);
    unsigned short* dtw_bf = (unsigned short*)carve((size_t)DI * DI * 2);
    unsigned short* ow_bf  = (unsigned short*)carve((size_t)DM * DI * 2);
    unsigned short* bc_bf  = (unsigned short*)carve((size_t)2 * DSN * DI * 2);
    unsigned short* z_bf   = (unsigned short*)carve((size_t)MTOT * DI * 2);
    unsigned short* u_bf   = (unsigned short*)carve((size_t)MTOT * DI * 2);
    float*          dt_f   = (float*)carve((size_t)MTOT * DI * 4);
    float*          bc_f   = (float*)carve((size_t)MTOT * 2 * DSN * 4);
    unsigned short* y_bf   = (unsigned short*)carve((size_t)MTOT * DI * 2);
    float*          Pbuf   = (float*)carve((size_t)NC * BATCHN * DI * DSN * 4);
    float*          Sbuf   = (float*)carve((size_t)NC * BATCHN * DI * DSN * 4);
    float*          Ibuf   = (float*)carve((size_t)NC * BATCHN * DI * DSN * 4);
    float*          pc_f   = (float*)carve((size_t)BCKS * MTOT * 32 * 4);

    // converts
    cvt_x_pad<<<MTOT * DM / 4 / 256, 256, 0, stream>>>(x, xpad);
    zero_pad<<<(BATCHN * 3 * DM + 255) / 256, 256, 0, stream>>>(xpad);
    cvt_convw<<<DI * DI / 256, 256, 0, stream>>>(convw, wk_bf);
    tp_cvt<<<dim3(DM / 32, DI / 32), 256, 0, stream>>>(ipw, Pt_bf);
    cvt_f32_bf16<<<DI * DM / 4 / 256, 256, 0, stream>>>(ipw + (size_t)DI * DM, ipz_bf, DI * DM / 4);
    cvt_f32_bf16<<<DI * DI / 4 / 256, 256, 0, stream>>>(dtw, dtw_bf, DI * DI / 4);
    cvt_f32_bf16<<<DM * DI / 4 / 256, 256, 0, stream>>>(ow, ow_bf, DM * DI / 4);
    cvt_f32_bf16<<<(DSN * DI / 4 + 255) / 256, 256, 0, stream>>>(bw, bc_bf, DSN * DI / 4);
    cvt_f32_bf16<<<(DSN * DI / 4 + 255) / 256, 256, 0, stream>>>(cwm, bc_bf + (size_t)DSN * DI, DSN * DI / 4);

    // mk-fuse: Mk = W_k @ P_xc   [2048][1024] x4 planes
    gemm_bt<4><<<dim3(8, 16, 4), 256, 0, stream>>>(wk_bf, Pt_bf, nullptr, mk_bf, nullptr, DI);
    // z-proj: z = x @ ipz^T
    gemm_bt<0><<<dim3(16, 32), 256, 0, stream>>>(xpad, ipz_bf, nullptr, z_bf, nullptr, DM);
    // conv (fused): u = sum_k x[l-3+k] @ Mk^T + conv_b
    gemm_bt<1><<<dim3(16, 32), 256, 0, stream>>>(xpad, mk_bf, convb, u_bf, nullptr, DM);
    // B/C projection: MFMA split-K + reduce
    bc_mfma<<<dim3(BCKS, MTOT / 128), 256, 0, stream>>>(u_bf, bc_bf, pc_f);
    bc_reduce<<<MTOT * 32 / 4 / 256, 256, 0, stream>>>(pc_f, bc_f);
    // dt projection + sigmoid/clip
    gemm_bt<2><<<dim3(16, 32), 256, 0, stream>>>(u_bf, dtw_bf, dtb, nullptr, dt_f, DI);
    // chunked scan
    scan_p1<<<BATCHN * 8 * NC, 256, 0, stream>>>(dt_f, u_bf, bc_f, alog, Pbuf, Sbuf);
    scan_p2<<<BATCHN * DI * DSN / 256, 256, 0, stream>>>(Pbuf, Sbuf, Ibuf);
    scan_p3<<<BATCHN * 8 * NC, 256, 0, stream>>>(dt_f, u_bf, bc_f, z_bf, alog, dvec, Ibuf, y_bf);
    // out projection
    gemm_bt<3><<<dim3(8, 32), 256, 0, stream>>>(y_bf, ow_bf, nullptr, nullptr, out, DI);
}